// Round 2
// baseline (906.612 us; speedup 1.0000x reference)
//
#include <hip/hip_runtime.h>
#include <hip/hip_bf16.h>
#include <math.h>

#define DI __device__ __forceinline__

constexpr int cB = 64, cL = 256, cD = 768;
constexpr long BLD = (long)cB * cL * cD;   // 12,582,912
constexpr long BLL = (long)cB * cL * cL;   //  4,194,304
constexpr long cLL = (long)cL * cL;
constexpr long cLD = (long)cL * cD;

typedef __attribute__((ext_vector_type(8))) short b8;
typedef __attribute__((ext_vector_type(4))) float f4;

// async global->LDS, 16B per lane, dest = wave-uniform base + lane*16 (linear)
#define GLDS(g, l)                                                    \
  __builtin_amdgcn_global_load_lds(                                   \
      (const __attribute__((address_space(1))) void*)(g),             \
      (__attribute__((address_space(3))) void*)(l), 16, 0, 0)

// ---------------- reductions (wave64) ----------------
DI float wsum(float v) {
#pragma unroll
  for (int o = 32; o > 0; o >>= 1) v += __shfl_down(v, o, 64);
  return v;
}
DI float wsum_all(float v) {
#pragma unroll
  for (int m = 32; m > 0; m >>= 1) v += __shfl_xor(v, m, 64);
  return v;
}
DI float wmax_all(float v) {
#pragma unroll
  for (int m = 32; m > 0; m >>= 1) v = fmaxf(v, __shfl_xor(v, m, 64));
  return v;
}
DI float wmaxr(float v) {
#pragma unroll
  for (int o = 32; o > 0; o >>= 1) v = fmaxf(v, __shfl_down(v, o, 64));
  return v;
}
DI float blockSum(float v) {
  __shared__ float sh[4];
  v = wsum(v);
  __syncthreads();
  if ((threadIdx.x & 63) == 0) sh[threadIdx.x >> 6] = v;
  __syncthreads();
  return sh[0] + sh[1] + sh[2] + sh[3];
}
DI float blockMax(float v) {
  __shared__ float sh[4];
  v = wmaxr(v);
  __syncthreads();
  if ((threadIdx.x & 63) == 0) sh[threadIdx.x >> 6] = v;
  __syncthreads();
  return fmaxf(fmaxf(sh[0], sh[1]), fmaxf(sh[2], sh[3]));
}
DI float sigf(float x) { return 1.f / (1.f + expf(-x)); }

// ================= bf16 MFMA GEMM: C = A(MxK) @ BT(NxK)^T =================
// 128x128 tile, 4 waves, 4x4 of 16x16x32 frags/wave, BK=32.
// Double-buffered LDS + global_load_lds(16B): prefetch K-tile t+1 is issued
// BEFORE computing tile t; ONE barrier per K-step. The barrier's vmcnt(0)
// drain then waits on loads that had the whole compute phase in flight.
// EPI: 0=plain (OBF/RELU), 2=H-update (relu -> gate vs auxf=H, write auxb bf16),
//      3=split-K f32 atomicAdd, 4=transposed bf16 write (per-256-row batch).
template <int OBF, int RELU, int BIAS, int EPI>
__global__ __launch_bounds__(256, 2) void bgemm(
    const __hip_bfloat16* __restrict__ A, const __hip_bfloat16* __restrict__ BT,
    void* __restrict__ Cv, const float* __restrict__ bias,
    float* __restrict__ auxf, __hip_bfloat16* __restrict__ auxb,
    int K, int lda, int ldb, int ldc,
    int zshift, int zmask, long sA1, long sA2, long sB1, long sB2, long sC,
    int czdiv) {
  __shared__ __hip_bfloat16 Asp[2][128 * 32];
  __shared__ __hip_bfloat16 Bsp[2][128 * 32];
  int z = blockIdx.z;
  A += (long)(z >> zshift) * sA1 + (long)(z & zmask) * sA2;
  BT += (long)(z >> zshift) * sB1 + (long)(z & zmask) * sB2;
  int tid = threadIdx.x;
  int lane = tid & 63, w = tid >> 6;
  int wr = w >> 1, wc = w & 1;
  int l16 = lane & 15, q = lane >> 4;
  int m0 = blockIdx.y << 7, n0 = blockIdx.x << 7;

  // staging: thread t loads row (t>>2), k-octet (t&3); lands at LDS byte t*16
  int fm = tid >> 2, fq = tid & 3;
  const __hip_bfloat16* Ap0 = A + (long)(m0 + fm) * lda + fq * 8;
  const __hip_bfloat16* Ap1 = A + (long)(m0 + fm + 64) * lda + fq * 8;
  const __hip_bfloat16* Bp0 = BT + (long)(n0 + fm) * ldb + fq * 8;
  const __hip_bfloat16* Bp1 = BT + (long)(n0 + fm + 64) * ldb + fq * 8;
  char* Aw0 = (char*)Asp + (w << 10);
  char* Aw1 = (char*)Asp + 4096 + (w << 10);
  char* Bw0 = (char*)Bsp + (w << 10);
  char* Bw1 = (char*)Bsp + 4096 + (w << 10);

  f4 acc[4][4];
#pragma unroll
  for (int i = 0; i < 4; i++)
#pragma unroll
    for (int j = 0; j < 4; j++) acc[i][j] = (f4){0.f, 0.f, 0.f, 0.f};

  // prologue: stage tile 0 into buf 0
  GLDS(Ap0, Aw0);
  GLDS(Ap1, Aw1);
  GLDS(Bp0, Bw0);
  GLDS(Bp1, Bw1);
  __syncthreads();
  int cur = 0;
  for (int k0 = 0; k0 < K; k0 += 32) {
    int k1 = k0 + 32;
    if (k1 < K) {  // issue prefetch of next tile into the other buffer
      int nb = (cur ^ 1) * 8192;
      GLDS(Ap0 + k1, Aw0 + nb);
      GLDS(Ap1 + k1, Aw1 + nb);
      GLDS(Bp0 + k1, Bw0 + nb);
      GLDS(Bp1 + k1, Bw1 + nb);
    }
    const __hip_bfloat16* As = Asp[cur];
    const __hip_bfloat16* Bs = Bsp[cur];
    b8 af[4], bf[4];
#pragma unroll
    for (int i = 0; i < 4; i++)
      af[i] = *(const b8*)&As[(wr * 64 + i * 16 + l16) * 32 + q * 8];
#pragma unroll
    for (int j = 0; j < 4; j++)
      bf[j] = *(const b8*)&Bs[(wc * 64 + j * 16 + l16) * 32 + q * 8];
#pragma unroll
    for (int i = 0; i < 4; i++)
#pragma unroll
      for (int j = 0; j < 4; j++)
        acc[i][j] = __builtin_amdgcn_mfma_f32_16x16x32_bf16(af[i], bf[j], acc[i][j], 0, 0, 0);
    __syncthreads();  // drains vmcnt(0): prefetch (in flight during MFMA) lands
    cur ^= 1;
  }
  if (EPI == 4) {
    // transposed bf16 write: C[b][n][l], b = m>>8, l = m&255, 4 l's per lane
#pragma unroll
    for (int j = 0; j < 4; j++) {
      int n = n0 + wc * 64 + j * 16 + l16;
#pragma unroll
      for (int i = 0; i < 4; i++) {
        int m = m0 + wr * 64 + i * 16 + (q << 2);
        __hip_bfloat16 t4[4];
#pragma unroll
        for (int r = 0; r < 4; r++) t4[r] = __float2bfloat16(acc[i][j][r]);
        long bidx = (long)(m >> 8) * sC + (long)n * cL + (m & 255);
        *(uint2*)&((__hip_bfloat16*)Cv)[bidx] = *(uint2*)t4;
      }
    }
    return;
  }
  long cz = (long)(z >> czdiv) * sC;
#pragma unroll
  for (int j = 0; j < 4; j++) {
    int n = n0 + wc * 64 + j * 16 + l16;
    float bv = BIAS ? bias[n] : 0.f;
#pragma unroll
    for (int i = 0; i < 4; i++) {
#pragma unroll
      for (int r = 0; r < 4; r++) {
        int m = m0 + wr * 64 + i * 16 + q * 4 + r;
        long idx = cz + (long)m * ldc + n;
        float v = acc[i][j][r] + bv;
        if (EPI == 0) {
          if (RELU) v = fmaxf(v, 0.f);
          if (OBF)
            ((__hip_bfloat16*)Cv)[idx] = __float2bfloat16(v);
          else
            ((float*)Cv)[idx] = v;
        } else if (EPI == 3) {
          atomicAdd(&((float*)Cv)[idx], v);
        } else {
          // EPI==2: v = Hout = relu(acc+bias); H' = H + sig(H)*(Hout - H)
          v = fmaxf(v, 0.f);
          float h = auxf[idx];
          float g = sigf(h);
          float o = h + g * (v - h);
          auxf[idx] = o;
          auxb[idx] = __float2bfloat16(o);
        }
      }
    }
  }
}

// ======== dual adjacency GEMM: Isem/Ilat share BT; fused I_com epilogue ========
// C1 = adjag @ HW + b ; C2 = adjlat @ HW + b ; Icb = bf16(C1 + 0.5*sig(C2)*(C2-C1))
// z = batch. A1,A2: (b,L,L) bf16, BT: HW^T (b,D,L) bf16. K = 256.
// Same double-buffered prefetch structure as bgemm.
__global__ __launch_bounds__(256, 2) void bgemm_dual(
    const __hip_bfloat16* __restrict__ A1g, const __hip_bfloat16* __restrict__ A2g,
    const __hip_bfloat16* __restrict__ BTg, float* __restrict__ IsemF,
    __hip_bfloat16* __restrict__ Icb, const float* __restrict__ bias,
    int write_isem) {
  __shared__ __hip_bfloat16 A1sp[2][128 * 32];
  __shared__ __hip_bfloat16 A2sp[2][128 * 32];
  __shared__ __hip_bfloat16 Bsp[2][128 * 32];
  int z = blockIdx.z;
  const __hip_bfloat16* A1 = A1g + (long)z * cLL;
  const __hip_bfloat16* A2 = A2g + (long)z * cLL;
  const __hip_bfloat16* BT = BTg + (long)z * cLD;
  int tid = threadIdx.x;
  int lane = tid & 63, w = tid >> 6;
  int wr = w >> 1, wc = w & 1;
  int l16 = lane & 15, q = lane >> 4;
  int m0 = blockIdx.y << 7, n0 = blockIdx.x << 7;

  int fm = tid >> 2, fq = tid & 3;
  const __hip_bfloat16* A1p0 = A1 + (long)(m0 + fm) * cL + fq * 8;
  const __hip_bfloat16* A1p1 = A1p0 + 64L * cL;
  const __hip_bfloat16* A2p0 = A2 + (long)(m0 + fm) * cL + fq * 8;
  const __hip_bfloat16* A2p1 = A2p0 + 64L * cL;
  const __hip_bfloat16* Bp0 = BT + (long)(n0 + fm) * cL + fq * 8;
  const __hip_bfloat16* Bp1 = Bp0 + 64L * cL;
  char* w10 = (char*)A1sp + (w << 10);
  char* w11 = (char*)A1sp + 4096 + (w << 10);
  char* w20 = (char*)A2sp + (w << 10);
  char* w21 = (char*)A2sp + 4096 + (w << 10);
  char* wb0 = (char*)Bsp + (w << 10);
  char* wb1 = (char*)Bsp + 4096 + (w << 10);

  f4 ac1[4][4], ac2[4][4];
#pragma unroll
  for (int i = 0; i < 4; i++)
#pragma unroll
    for (int j = 0; j < 4; j++) {
      ac1[i][j] = (f4){0.f, 0.f, 0.f, 0.f};
      ac2[i][j] = (f4){0.f, 0.f, 0.f, 0.f};
    }

  GLDS(A1p0, w10);
  GLDS(A1p1, w11);
  GLDS(A2p0, w20);
  GLDS(A2p1, w21);
  GLDS(Bp0, wb0);
  GLDS(Bp1, wb1);
  __syncthreads();
  int cur = 0;
  for (int k0 = 0; k0 < cL; k0 += 32) {
    int k1 = k0 + 32;
    if (k1 < cL) {
      int nb = (cur ^ 1) * 8192;
      GLDS(A1p0 + k1, w10 + nb);
      GLDS(A1p1 + k1, w11 + nb);
      GLDS(A2p0 + k1, w20 + nb);
      GLDS(A2p1 + k1, w21 + nb);
      GLDS(Bp0 + k1, wb0 + nb);
      GLDS(Bp1 + k1, wb1 + nb);
    }
    const __hip_bfloat16* A1s = A1sp[cur];
    const __hip_bfloat16* A2s = A2sp[cur];
    const __hip_bfloat16* Bs = Bsp[cur];
    b8 a1f[4], a2f[4], bf[4];
#pragma unroll
    for (int i = 0; i < 4; i++) {
      a1f[i] = *(const b8*)&A1s[(wr * 64 + i * 16 + l16) * 32 + q * 8];
      a2f[i] = *(const b8*)&A2s[(wr * 64 + i * 16 + l16) * 32 + q * 8];
    }
#pragma unroll
    for (int j = 0; j < 4; j++)
      bf[j] = *(const b8*)&Bs[(wc * 64 + j * 16 + l16) * 32 + q * 8];
#pragma unroll
    for (int i = 0; i < 4; i++)
#pragma unroll
      for (int j = 0; j < 4; j++) {
        ac1[i][j] = __builtin_amdgcn_mfma_f32_16x16x32_bf16(a1f[i], bf[j], ac1[i][j], 0, 0, 0);
        ac2[i][j] = __builtin_amdgcn_mfma_f32_16x16x32_bf16(a2f[i], bf[j], ac2[i][j], 0, 0, 0);
      }
    __syncthreads();
    cur ^= 1;
  }
  long cz = (long)z * cLD;
#pragma unroll
  for (int j = 0; j < 4; j++) {
    int n = n0 + wc * 64 + j * 16 + l16;
    float bv = bias[n];
#pragma unroll
    for (int i = 0; i < 4; i++) {
#pragma unroll
      for (int r = 0; r < 4; r++) {
        int m = m0 + wr * 64 + i * 16 + q * 4 + r;
        long idx = cz + (long)m * cD + n;
        float is = ac1[i][j][r] + bv;
        float il = ac2[i][j][r] + bv;
        float g = 0.5f * sigf(il);
        Icb[idx] = __float2bfloat16(is + g * (il - is));
        if (write_isem) IsemF[idx] = is;
      }
    }
  }
}

// ---------------- 7 weight convert+transpose in one dispatch ----------------
__global__ void k_wconv7(const float* __restrict__ s0, const float* __restrict__ s1,
                         const float* __restrict__ s2, const float* __restrict__ s3,
                         const float* __restrict__ s4, const float* __restrict__ s5,
                         const float* __restrict__ s6, __hip_bfloat16* __restrict__ dst) {
  const float* srcs[7] = {s0, s1, s2, s3, s4, s5, s6};
  const float* src = srcs[blockIdx.z];
  __hip_bfloat16* d = dst + (long)blockIdx.z * cD * cD;
  __shared__ float t[32][33];
  int k0 = blockIdx.x * 32, n0 = blockIdx.y * 32;
  int tx = threadIdx.x, ty = threadIdx.y;
#pragma unroll
  for (int i = 0; i < 32; i += 8) t[ty + i][tx] = src[(long)(k0 + ty + i) * cD + n0 + tx];
  __syncthreads();
#pragma unroll
  for (int i = 0; i < 32; i += 8)
    d[(long)(n0 + ty + i) * cD + k0 + tx] = __float2bfloat16(t[tx][ty + i]);
}

// ---------------- embedding + layernorm + fused root dot; pre-LN x for l==0 ----------------
__global__ __launch_bounds__(256) void k_gcnin(
    const int* __restrict__ tbi, const int* __restrict__ bsi,
    const float* __restrict__ tok, const float* __restrict__ seg,
    const float* __restrict__ ln_a, const float* __restrict__ ln_b,
    const float* __restrict__ root_w,
    float* __restrict__ gcn_in, __hip_bfloat16* __restrict__ gib,
    float* __restrict__ x64, float* __restrict__ e1) {
  long bl = blockIdx.x;
  int t = tbi[bl], s = bsi[bl];
  const float* tr = tok + (long)t * cD;
  const float* sr = seg + (long)s * cD;
  float x[3];
  float ls = 0.f;
#pragma unroll
  for (int i = 0; i < 3; i++) {
    int d = threadIdx.x + (i << 8);
    x[i] = tr[d] + sr[d];
    ls += x[i];
  }
  if ((bl & 255) == 0) {
#pragma unroll
    for (int i = 0; i < 3; i++) x64[(bl >> 8) * cD + threadIdx.x + (i << 8)] = x[i];
  }
  float mean = blockSum(ls) * (1.f / 768.f);
  float lv = 0.f;
#pragma unroll
  for (int i = 0; i < 3; i++) { float c = x[i] - mean; lv += c * c; }
  float var = blockSum(lv) * (1.f / 767.f);
  float inv = 1.f / (sqrtf(var) + 1e-6f);
  float rdot = 0.f;
#pragma unroll
  for (int i = 0; i < 3; i++) {
    int d = threadIdx.x + (i << 8);
    float v = ln_a[d] * (x[i] - mean) * inv + ln_b[d];
    gcn_in[bl * cD + d] = v;
    gib[bl * cD + d] = __float2bfloat16(v);
    rdot += v * root_w[d];
  }
  float tot = blockSum(rdot);
  if (threadIdx.x == 0) e1[bl] = tot;
}

// ---------------- pooled GEMV partials ----------------
__global__ __launch_bounds__(256) void k_pool1(
    const float* __restrict__ x64, const float* __restrict__ pw,
    float* __restrict__ pacc) {
  __shared__ float pws[48][256];
  __shared__ float xs[16][48];
  int i0 = blockIdx.x * 48, j0 = blockIdx.y * 256, b0 = blockIdx.z * 16;
  for (int r = 0; r < 48; r++) pws[r][threadIdx.x] = pw[(long)(i0 + r) * cD + j0 + threadIdx.x];
  for (int idx = threadIdx.x; idx < 16 * 48; idx += 256)
    xs[idx / 48][idx % 48] = x64[(long)(b0 + idx / 48) * cD + i0 + idx % 48];
  __syncthreads();
  int j = threadIdx.x;
  for (int b = 0; b < 16; b++) {
    float acc = 0.f;
#pragma unroll 8
    for (int i = 0; i < 48; i++) acc += xs[b][i] * pws[i][j];
    atomicAdd(&pacc[(long)(b0 + b) * cD + j0 + j], acc);
  }
}
__global__ __launch_bounds__(256) void k_pool2(
    const float* __restrict__ pacc, const float* __restrict__ pb,
    float* __restrict__ pooled) {
  int b = blockIdx.x;
#pragma unroll
  for (int c = 0; c < 3; c++) {
    int j = (c << 8) + threadIdx.x;
    pooled[(long)b * cD + j] = tanhf(pacc[(long)b * cD + j] + pb[j]);
  }
}

// ---------------- dep LUT ----------------
__global__ __launch_bounds__(256) void k_s45(
    const float* __restrict__ dep_emb, const float* __restrict__ fc1w,
    const float* __restrict__ fc1b, const float* __restrict__ fc2w,
    const float* __restrict__ fc2b, float* __restrict__ s45) {
  int t = blockIdx.x;
  __shared__ float e[300];
  for (int i = threadIdx.x; i < 300; i += 256) e[i] = dep_emb[t * 300 + i];
  __syncthreads();
  int j = threadIdx.x;
  float h = fc1b[j];
  for (int i = 0; i < 300; i++) h += e[i] * fc1w[i * 256 + j];
  h = fmaxf(h, 0.f);
  float tot = blockSum(h * fc2w[j]);
  if (threadIdx.x == 0) s45[t] = tot + fc2b[0];
}

__global__ __launch_bounds__(256) void k_depfeat(
    const int* __restrict__ ori, const float* __restrict__ src_mask,
    const float* __restrict__ s45, float* __restrict__ dep_feat) {
  int b = blockIdx.x, l = threadIdx.x;
  float smv = (l == 0) ? 1.f : src_mask[b * cL + l];
  float sc = s45[ori[b * cL + l]] * smv + (1.f - smv) * (-1e30f);
  float mx = blockMax(sc);
  float ex = expf(sc - mx);
  float sum = blockSum(ex);
  dep_feat[b * cL + l] = ex / sum;
}

// ---------------- bias concat for fused projection ----------------
__global__ void k_bcat(const float* __restrict__ a, const float* __restrict__ b,
                       const float* __restrict__ c, const float* __restrict__ d,
                       float* __restrict__ o) {
  int i = blockIdx.x * 256 + threadIdx.x;
  float v = (i < 768) ? a[i] : (i < 1536) ? b[i - 768] : (i < 2304) ? c[i - 1536] : d[i - 2304];
  o[i] = v;
}

// ---------------- adj_ag softmax (bf16 scores in) ----------------
__global__ __launch_bounds__(256) void k_adjag_sm(
    const __hip_bfloat16* __restrict__ scores, const float* __restrict__ src_mask,
    __hip_bfloat16* __restrict__ adjag) {
  int b = blockIdx.x >> 8, i = blockIdx.x & 255;
  int tid = threadIdx.x, wave = tid >> 6, lane = tid & 63;
  __shared__ float accs[4][256];
  const float scale = 1.f / (sqrtf(96.f) + 1e-9f);
  float smj[4], acc[4];
#pragma unroll
  for (int c = 0; c < 4; c++) {
    int j = c * 64 + lane;
    smj[c] = (j == 0) ? 1.f : src_mask[b * cL + j];
    acc[c] = 0.f;
  }
  for (int hh = 0; hh < 2; hh++) {
    int h = wave * 2 + hh;
    const __hip_bfloat16* row = scores + (((long)(b * 8 + h)) * cL + i) * cL;
    float s[4], m = -1e30f;
#pragma unroll
    for (int c = 0; c < 4; c++) {
      s[c] = (smj[c] == 0.f) ? -1e9f : __bfloat162float(row[c * 64 + lane]) * scale;
      m = fmaxf(m, s[c]);
    }
    m = wmax_all(m);
    float es = 0.f;
#pragma unroll
    for (int c = 0; c < 4; c++) { s[c] = expf(s[c] - m); es += s[c]; }
    es = wsum_all(es);
    float inv = 1.f / es;
#pragma unroll
    for (int c = 0; c < 4; c++) acc[c] += s[c] * inv;
  }
#pragma unroll
  for (int c = 0; c < 4; c++) accs[wave][c * 64 + lane] = acc[c];
  __syncthreads();
  int j = tid;
  float tot = accs[0][j] + accs[1][j] + accs[2][j] + accs[3][j];
  float smi = (i == 0) ? 1.f : src_mask[b * cL + i];
  float v = (j == i) ? 1.f : tot * 0.125f;
  adjag[((long)b * cL + i) * cL + j] = __float2bfloat16(v * smi);
}

// ---------------- adj_latent softmax (f32 split-K scores) + inlined dep_adj ----------------
__global__ __launch_bounds__(256) void k_adjlat_sm(
    const float* __restrict__ latsc, const int* __restrict__ head,
    const float* __restrict__ df, const float* __restrict__ src_mask,
    __hip_bfloat16* __restrict__ adjlat) {
  int b = blockIdx.x >> 8, i = blockIdx.x & 255;
  int j = threadIdx.x;
  float smj = (j == 0) ? 1.f : src_mask[b * cL + j];
  float dep = 1.f;
  if (j >= 1 && head[b * cL + j - 1] == i) dep = df[b * cL + j - 1];
  if (i >= 1 && j == head[b * cL + i - 1]) dep = df[b * cL + i - 1];
  float s = latsc[((long)b * cL + i) * cL + j] * (1.f / sqrtf(768.f)) +
            dep + (1.f - smj) * (-10000.f);
  float mx = blockMax(s);
  float ex = expf(s - mx);
  float sum = blockSum(ex);
  float p = ex / sum;
  float smi = (i == 0) ? 1.f : src_mask[b * cL + i];
  adjlat[((long)b * cL + i) * cL + j] = __float2bfloat16(((j == i) ? 1.f : p) * smi);
}

// ---------------- wave-per-row dot ----------------
__global__ __launch_bounds__(256) void k_rowdot(
    const float* __restrict__ X, const float* __restrict__ w, long wstride,
    float* __restrict__ e) {
  int r = blockIdx.x * 4 + (threadIdx.x >> 6);
  int lane = threadIdx.x & 63;
  const float4* row = (const float4*)(X + (long)r * cD);
  const float4* wp = (const float4*)(w + (long)(r >> 8) * wstride);
  float s = 0.f;
#pragma unroll
  for (int c = 0; c < 3; c++) {
    int idx = c * 64 + lane;
    float4 a = row[idx], b = wp[idx];
    s += a.x * b.x + a.y * b.y + a.z * b.z + a.w * b.w;
  }
  s = wsum(s);
  if (lane == 0) e[r] = s;
}

// ---------------- root loss ----------------
__global__ __launch_bounds__(256) void k_root2(
    const float* __restrict__ e1, const float* __restrict__ src_mask,
    const float* __restrict__ aspect_mask, float* __restrict__ out_loss) {
  int b = blockIdx.x, l = threadIdx.x;
  float r = e1[b * cL + l];
  float smv = (l == 0) ? 1.f : src_mask[b * cL + l];
  float sc = r * smv + (1.f - smv) * (-1e30f);
  float mx = blockMax(sc);
  float ex = expf(sc - mx);
  float sum = blockSum(ex);
  float p = ex / sum;
  float tot = blockSum(p * aspect_mask[b * cL + l]);
  if (l == 0) atomicAdd(out_loss, -logf(tot + 1e-9f) * (1.f / 64.f));
}

// ---------------- lexicon loss ----------------
__global__ __launch_bounds__(256) void k_lex2(
    const float* __restrict__ e2, const float* __restrict__ src_mask,
    const float* __restrict__ lex, float* __restrict__ out_loss) {
  int b = blockIdx.x, l = threadIdx.x;
  float e = e2[b * cL + l];
  float mx = blockMax(e);
  float ex = expf(e - mx);
  float sum = blockSum(ex);
  float mult = (l == 0) ? 0.f : src_mask[b * cL + l];
  float lw = ex / sum * 50.f * mult;
  float d2 = lw - lex[b * cL + l];
  float tot = blockSum(d2 * d2);
  if (l == 0) atomicAdd(out_loss, tot * (1.f / (64.f * 256.f)));
}

// ---------------- hlsum partials ----------------
__global__ __launch_bounds__(256) void k_hl(
    const float* __restrict__ H, const float* __restrict__ src_mask,
    float* __restrict__ hlsum) {
  int b = blockIdx.z, d = (blockIdx.y << 8) + threadIdx.x, l0 = blockIdx.x * 32;
  float acc = 0.f;
  for (int l = l0; l < l0 + 32; l++) {
    float smv = (l == 0) ? 1.f : src_mask[b * cL + l];
    acc += H[((long)b * cL + l) * cD + d] * smv;
  }
  atomicAdd(&hlsum[(long)b * cD + d], acc);
}

// ---------------- attn weights + asum ----------------
__global__ __launch_bounds__(256) void k_attnw(
    const float* __restrict__ sraw, const float* __restrict__ src_mask,
    const float* __restrict__ am, float* __restrict__ wgt, float* __restrict__ asum) {
  int b = blockIdx.x, k = threadIdx.x;
  float smk = (k == 0) ? 1.f : src_mask[b * cL + k];
  float s = sraw[b * cL + k] * smk * 0.001f;
  float mx = blockMax(s);
  float ex = expf(s - mx);
  float sum = blockSum(ex);
  wgt[b * cL + k] = ex / sum;
  float a = blockSum(am[b * cL + k]);
  if (k == 0) asum[b] = a;
}

// ---------------- fused outputs+sempool partials ----------------
__global__ __launch_bounds__(256) void k_wsum(
    const float* __restrict__ Isem, const float* __restrict__ wgt,
    const float* __restrict__ am, float* __restrict__ outputs,
    float* __restrict__ sempool) {
  int b = blockIdx.z, d = (blockIdx.y << 8) + threadIdx.x, l0 = blockIdx.x * 32;
  float accO = 0.f, accS = 0.f;
  for (int l = l0; l < l0 + 32; l++) {
    float v = Isem[((long)b * cL + l) * cD + d];
    accO += wgt[b * cL + l] * v;
    accS += am[b * cL + l] * v;
  }
  atomicAdd(&outputs[(long)b * cD + d], accO);
  atomicAdd(&sempool[(long)b * cD + d], accS);
}

// ---------------- logits ----------------
__global__ __launch_bounds__(256) void k_logits(
    const float* __restrict__ outputs, const float* __restrict__ sempool,
    const float* __restrict__ pooled, const float* __restrict__ asum,
    const float* __restrict__ cw, const float* __restrict__ cb,
    float* __restrict__ out) {
  int b = blockIdx.x;
  float inv = 1.f / (asum[b] + 1e-9f);
  float a0 = 0.f, a1 = 0.f, a2 = 0.f;
  for (int i = threadIdx.x; i < 3 * cD; i += 256) {
    float f = (i < cD) ? outputs[(long)b * cD + i]
              : (i < 2 * cD) ? sempool[(long)b * cD + i - cD] * inv
                             : pooled[(long)b * cD + i - 2 * cD];
    a0 += f * cw[i * 3 + 0];
    a1 += f * cw[i * 3 + 1];
    a2 += f * cw[i * 3 + 2];
  }
  a0 = blockSum(a0);
  a1 = blockSum(a1);
  a2 = blockSum(a2);
  if (threadIdx.x == 0) {
    out[b * 3 + 0] = a0 + cb[0];
    out[b * 3 + 1] = a1 + cb[1];
    out[b * 3 + 2] = a2 + cb[2];
  }
}

extern "C" void kernel_launch(void* const* d_in, const int* in_sizes, int n_in,
                              void* d_out, int out_size, void* d_ws, size_t ws_size,
                              hipStream_t stream) {
  const int* tbi = (const int*)d_in[0];
  const int* bsi = (const int*)d_in[1];
  const float* src_mask = (const float*)d_in[3];
  const float* aspect_mask = (const float*)d_in[4];
  const float* lex = (const float*)d_in[5];
  const int* ori = (const int*)d_in[6];
  const int* head = (const int*)d_in[7];
  const float* tok_emb = (const float*)d_in[8];
  const float* seg_emb = (const float*)d_in[9];
  const float* pool_w = (const float*)d_in[10];
  const float* pool_b = (const float*)d_in[11];
  const float* ln_a = (const float*)d_in[12];
  const float* ln_b = (const float*)d_in[13];
  const float* dep_emb = (const float*)d_in[14];
  const float* fc1_w = (const float*)d_in[15];
  const float* fc1_b = (const float*)d_in[16];
  const float* fc2_w = (const float*)d_in[17];
  const float* fc2_b = (const float*)d_in[18];
  const float* aq_w = (const float*)d_in[19];
  const float* aq_b = (const float*)d_in[20];
  const float* ak_w = (const float*)d_in[21];
  const float* ak_b = (const float*)d_in[22];
  const float* lq_w = (const float*)d_in[23];
  const float* lq_b = (const float*)d_in[24];
  const float* lk_w = (const float*)d_in[25];
  const float* lk_b = (const float*)d_in[26];
  const float* root_w = (const float*)d_in[27];
  const float* gcn_w = (const float*)d_in[28];
  const float* gcn_b = (const float*)d_in[29];
  const float* fc3_w = (const float*)d_in[30];
  const float* fc3_b = (const float*)d_in[31];
  const float* cls_w = (const float*)d_in[32];
  const float* cls_b = (const float*)d_in[33];
  const float* vlin_w = (const float*)d_in[34];

  float* out = (float*)d_out;
  float* ws = (float*)d_ws;
  // fp32 region
  float* gcnH = ws;            // BLD (gcn_in -> H_l)
  float* Isem = gcnH + BLD;    // BLD  (also latsc f32 alias pre-loop)
  float* depfeat = Isem + BLD;         // B*L
  float* s45 = depfeat + cB * cL;      // 64
  float* pooled = s45 + 64;            // B*D
  float* x64 = pooled + cB * cD;       // B*D
  float* hlsum = x64 + cB * cD;        // B*D  --- zeroed region start
  float* outputs = hlsum + cB * cD;    // B*D
  float* sempool = outputs + cB * cD;  // B*D
  float* pacc = sempool + cB * cD;     // B*D  --- zeroed region end
  float* e1 = pacc + cB * cD;          // B*L
  float* e2 = e1 + cB * cL;            // B*L
  float* sraw = e2 + cB * cL;          // B*L
  float* wgt = sraw + cB * cL;         // B*L
  float* asum = wgt + cB * cL;         // 64
  float* catb = asum + 64;             // 3072
  float* latsc = Isem;                 // BLL f32 alias (dead until GCN loop)
  // bf16 region
  __hip_bfloat16* gib = (__hip_bfloat16*)(catb + 3072);  // BLD
  __hip_bfloat16* qkb = gib + BLD;             // 4*BLD (q|k|q2|k2, ldc=3072)
  __hip_bfloat16* scores = qkb + 4 * BLD;      // 8*BLL
  __hip_bfloat16* adjag_b = scores + 8 * BLL;  // BLL
  __hip_bfloat16* adjlat_b = adjag_b + BLL;    // BLL
  __hip_bfloat16* wbt = adjlat_b + BLL;        // 7*D*D
  // aliases
  __hip_bfloat16* HWbT = qkb + BLD;     // BLD (HW^T, written directly by EPI=4)
  __hip_bfloat16* Icb = qkb + 2 * BLD;  // BLD

  hipMemsetAsync((char*)d_out + 192 * sizeof(float), 0, 2 * sizeof(float), stream);
  hipMemsetAsync(hlsum, 0, 4 * cB * cD * sizeof(float), stream);
  hipMemsetAsync(latsc, 0, BLL * sizeof(float), stream);  // split-K accumulator

  // ---- prologue ----
  k_gcnin<<<cB * cL, 256, 0, stream>>>(tbi, bsi, tok_emb, seg_emb, ln_a, ln_b,
                                       root_w, gcnH, gib, x64, e1);
  k_s45<<<45, 256, 0, stream>>>(dep_emb, fc1_w, fc1_b, fc2_w, fc2_b, s45);
  k_depfeat<<<cB, 256, 0, stream>>>(ori, src_mask, s45, depfeat);
  k_pool1<<<dim3(16, 3, 4), 256, 0, stream>>>(x64, pool_w, pacc);
  k_pool2<<<cB, 256, 0, stream>>>(pacc, pool_b, pooled);
  k_bcat<<<12, 256, 0, stream>>>(aq_b, ak_b, lq_b, lk_b, catb);
  k_wconv7<<<dim3(24, 24, 7), dim3(32, 8), 0, stream>>>(
      aq_w, ak_w, lq_w, lk_w, gcn_w, gcn_w + (long)cD * cD, fc3_w, wbt);

  const long DD = (long)cD * cD;
  const long LD = cLD, LL = cLL;
  const long LP = (long)cL * 3072;  // qkb batch stride

  // ---- fused 4-way projection: qkb = gib @ [aq|ak|lq|lk] + catb ----
  bgemm<1, 0, 1, 0><<<dim3(24, 128, 1), 256, 0, stream>>>(
      gib, wbt, qkb, catb, nullptr, nullptr, cD, cD, cD, 3072,
      0, 0, 0, 0, 0, 0, 0, 0);

  // ---- head scores (bf16 out) + adj_ag softmax ----
  bgemm<1, 0, 0, 0><<<dim3(2, 2, cB * 8), 256, 0, stream>>>(
      qkb, qkb + 768, scores, nullptr, nullptr, nullptr,
      96, 3072, 3072, cL, 3, 7, LP, 96, LP, 96, LL, 0);
  k_adjag_sm<<<cB * cL, 256, 0, stream>>>(scores, src_mask, adjag_b);

  // ---- latent scores: split-K (2x384) f32 atomicAdd + adj_latent softmax ----
  bgemm<0, 0, 0, 3><<<dim3(2, 2, cB * 2), 256, 0, stream>>>(
      qkb + 1536, qkb + 2304, latsc, nullptr, nullptr, nullptr,
      384, 3072, 3072, cL, 1, 1, LP, 384, LP, 384, LL, 1);
  k_adjlat_sm<<<cB * cL, 256, 0, stream>>>(latsc, head, depfeat, src_mask, adjlat_b);

  // ---- root loss (e1 fused into k_gcnin) ----
  k_root2<<<cB, 256, 0, stream>>>(e1, src_mask, aspect_mask, out + 192);

  // ---- GCN loop ----
  for (int layer = 0; layer < 2; layer++) {
    const float* bb = gcn_b + (long)layer * cD;
    // HW^T = (H @ W)^T written directly (EPI=4), layout (b, d, l)
    bgemm<1, 0, 0, 4><<<dim3(6, 128, 1), 256, 0, stream>>>(
        gib, wbt + (4 + layer) * DD, HWbT, nullptr, nullptr, nullptr,
        cD, cD, cD, cD, 0, 0, 0, 0, 0, 0, LD, 0);
    // dual adjacency GEMM + fused I_com epilogue (writes Isem f32 on last layer)
    bgemm_dual<<<dim3(6, 2, cB), 256, 0, stream>>>(
        adjag_b, adjlat_b, HWbT, Isem, Icb, bb, layer == 1 ? 1 : 0);
    // fc3 GEMM with fused H-gate epilogue: updates gcnH (f32) + gib (bf16)
    bgemm<0, 1, 1, 2><<<dim3(6, 128, 1), 256, 0, stream>>>(
        Icb, wbt + 6 * DD, nullptr, fc3_b, gcnH, gib,
        cD, cD, cD, cD, 0, 0, 0, 0, 0, 0, 0, 0);
  }

  // ---- tail ----
  k_hl<<<dim3(8, 3, cB), 256, 0, stream>>>(gcnH, src_mask, hlsum);
  k_rowdot<<<cB * cL / 4, 256, 0, stream>>>(Isem, hlsum, cD, sraw);
  k_attnw<<<cB, 256, 0, stream>>>(sraw, src_mask, aspect_mask, wgt, asum);
  k_wsum<<<dim3(8, 3, cB), 256, 0, stream>>>(Isem, wgt, aspect_mask, outputs, sempool);
  k_logits<<<cB, 256, 0, stream>>>(outputs, sempool, pooled, asum, cls_w, cls_b, out);
  k_rowdot<<<cB * cL / 4, 256, 0, stream>>>(gcnH, vlin_w, 0, e2);
  k_lex2<<<cB, 256, 0, stream>>>(e2, src_mask, lex, out + 193);
}

// Round 3
// 903.926 us; speedup vs baseline: 1.0030x; 1.0030x over previous
//
#include <hip/hip_runtime.h>
#include <hip/hip_bf16.h>
#include <math.h>

#define DI __device__ __forceinline__

constexpr int cB = 64, cL = 256, cD = 768;
constexpr long BLD = (long)cB * cL * cD;   // 12,582,912
constexpr long BLL = (long)cB * cL * cL;   //  4,194,304
constexpr long cLL = (long)cL * cL;
constexpr long cLD = (long)cL * cD;

typedef __attribute__((ext_vector_type(8))) short b8;
typedef __attribute__((ext_vector_type(4))) float f4;

// async global->LDS, 16B per lane, dest = wave-uniform base + lane*16 (linear)
#define GLDS(g, l)                                                    \
  __builtin_amdgcn_global_load_lds(                                   \
      (const __attribute__((address_space(1))) void*)(g),             \
      (__attribute__((address_space(3))) void*)(l), 16, 0, 0)

#define SCB __builtin_amdgcn_sched_barrier(0)
#define BAR()                        \
  {                                  \
    SCB;                             \
    __builtin_amdgcn_s_barrier();    \
    SCB;                             \
  }
#define VMC4 asm volatile("s_waitcnt vmcnt(4)" ::: "memory")
#define VMC0 asm volatile("s_waitcnt vmcnt(0)" ::: "memory")

// ---------------- reductions (wave64) ----------------
DI float wsum(float v) {
#pragma unroll
  for (int o = 32; o > 0; o >>= 1) v += __shfl_down(v, o, 64);
  return v;
}
DI float wsum_all(float v) {
#pragma unroll
  for (int m = 32; m > 0; m >>= 1) v += __shfl_xor(v, m, 64);
  return v;
}
DI float wmax_all(float v) {
#pragma unroll
  for (int m = 32; m > 0; m >>= 1) v = fmaxf(v, __shfl_xor(v, m, 64));
  return v;
}
DI float wmaxr(float v) {
#pragma unroll
  for (int o = 32; o > 0; o >>= 1) v = fmaxf(v, __shfl_down(v, o, 64));
  return v;
}
DI float blockSum(float v) {
  __shared__ float sh[4];
  v = wsum(v);
  __syncthreads();
  if ((threadIdx.x & 63) == 0) sh[threadIdx.x >> 6] = v;
  __syncthreads();
  return sh[0] + sh[1] + sh[2] + sh[3];
}
DI float blockMax(float v) {
  __shared__ float sh[4];
  v = wmaxr(v);
  __syncthreads();
  if ((threadIdx.x & 63) == 0) sh[threadIdx.x >> 6] = v;
  __syncthreads();
  return fmaxf(fmaxf(sh[0], sh[1]), fmaxf(sh[2], sh[3]));
}
DI float sigf(float x) { return 1.f / (1.f + expf(-x)); }

// ============ 256x256 phase-scheduled GEMM (projection only) ============
// C = A(16384x768) @ BT(3072x768)^T + bias, bf16 out, ldc=3072.
// 8 waves (2m x 4n), per-wave 128x64 out = 8x4 frags of 16x16x32.
// BK=64 as 2 k-halves; 4 phases per K-tile:
//   P1: ds_read A(ks0) x8 + B(ks0,j01) x2 | stage A(t+1,kh0) | bar | 16 MFMA | bar
//   P2: ds_read B(ks0,j23) x2             | stage B(t+1,kh0) | vmcnt(4) bar | 16 MFMA | bar
//   P3: ds_read A(ks1) x8 + B(ks1,j01) x2 | stage A(t+1,kh1) | bar | 16 MFMA | bar
//   P4: ds_read B(ks1,j23) x2             | stage B(t+1,kh1) | vmcnt(4) bar | 16 MFMA | bar
// vmcnt invariant (steady state): 8 loads outstanding at each even-phase
// checkpoint; vmcnt(4) lands exactly the 2 half-tiles the NEXT phase reads.
// Never 0 mid-loop (only on last tile where no staging is issued).
// Race audit: staging targets buf q=p^1 whose last reads finished before the
// trailing barrier of the previous tile; within-tile reads of buf p never
// alias staging (different buffer); all waves pass vmcnt before each barrier
// so landed-ness is global before any ds_read of staged data.
// LDS swizzle: physical = logical ^ (((logical>>7)&7)<<4). Involution (selector
// bits 7-9 disjoint from target bits 4-6), 16B-granular. Applied on the GLOBAL
// source address at stage time (gload_lds dest stays lane-linear) and on the
// ds_read address (rule #21). Spreads the 64B-row-stride frag reads across all
// 8 bank groups (2 lanes each = conflict-free).
__global__ __launch_bounds__(512, 2) void bgemm256(
    const __hip_bfloat16* __restrict__ A, const __hip_bfloat16* __restrict__ BT,
    __hip_bfloat16* __restrict__ C, const float* __restrict__ bias) {
  constexpr int K = 768, LDA = 768, LDB = 768, LDC = 3072, NT = K / 64;
  __shared__ __hip_bfloat16 lds[65536];  // 128 KiB: A 2buf x 2kh x 16KB | B same
  char* ldsA = (char*)lds;
  char* ldsB = (char*)lds + 65536;
  const int tid = threadIdx.x;
  const int lane = tid & 63, w = tid >> 6;
  const int wm = w >> 2, wn = w & 3;
  const int l16 = lane & 15, q4 = lane >> 4;
  const int m0 = blockIdx.y << 8, n0 = blockIdx.x << 8;

  // staging: thread stages 16B chunks ci = u*512+tid of each 16KB half-tile.
  // physical chunk ci receives global data for logical chunk L = f(ci*16).
  int goffA[2], goffB[2];
  char* stA[2];
  char* stB[2];
#pragma unroll
  for (int u = 0; u < 2; u++) {
    int ci = u * 512 + tid;
    int P = ci * 16;
    int Lb = P ^ (((P >> 7) & 7) << 4);
    int rowL = Lb >> 6, c16 = (Lb >> 4) & 3;
    goffA[u] = (m0 + rowL) * LDA + c16 * 8;
    goffB[u] = (n0 + rowL) * LDB + c16 * 8;
    stA[u] = ldsA + u * 8192 + (w << 10);  // HW adds lane*16
    stB[u] = ldsB + u * 8192 + (w << 10);
  }
  // per-lane swizzled ds_read offsets within a 16KB half (row-sel bits 1-3 = l16 bits 1-3)
  const int swzr = ((l16 >> 1) & 7) << 4;
  const int aoff = (((wm * 128 + l16) * 64) + q4 * 16) ^ swzr;
  const int boff = (((wn * 64 + l16) * 64) + q4 * 16) ^ swzr;

  f4 acc[8][4];
#pragma unroll
  for (int i = 0; i < 8; i++)
#pragma unroll
    for (int j = 0; j < 4; j++) acc[i][j] = (f4){0.f, 0.f, 0.f, 0.f};

#define STG(Gp, go, sd, bufo, kb)              \
  {                                            \
    GLDS(Gp + go[0] + (kb), sd[0] + (bufo));   \
    GLDS(Gp + go[1] + (kb), sd[1] + (bufo));   \
  }

  // prologue: tile 0, kh0 pair first (oldest -> landed by first vmcnt(4))
  STG(A, goffA, stA, 0, 0);
  STG(BT, goffB, stB, 0, 0);
  STG(A, goffA, stA, 16384, 32);
  STG(BT, goffB, stB, 16384, 32);
  VMC4;
  BAR();

  for (int t = 0; t < NT; ++t) {
    const int p = t & 1;
    const char* Ab = ldsA + p * 32768;
    const char* Bb = ldsB + p * 32768;
    const int qo = (p ^ 1) * 32768;
    const bool st = (t + 1 < NT);
    const int kn = (t + 1) * 64;
    b8 a[8], b0, b1;
    // ---- P1 ----
#pragma unroll
    for (int i = 0; i < 8; i++) a[i] = *(const b8*)(Ab + aoff + i * 1024);
    b0 = *(const b8*)(Bb + boff);
    b1 = *(const b8*)(Bb + boff + 1024);
    if (st) STG(A, goffA, stA, qo, kn);
    BAR();
    __builtin_amdgcn_s_setprio(1);
#pragma unroll
    for (int i = 0; i < 8; i++) {
      acc[i][0] = __builtin_amdgcn_mfma_f32_16x16x32_bf16(a[i], b0, acc[i][0], 0, 0, 0);
      acc[i][1] = __builtin_amdgcn_mfma_f32_16x16x32_bf16(a[i], b1, acc[i][1], 0, 0, 0);
    }
    __builtin_amdgcn_s_setprio(0);
    BAR();
    // ---- P2 ----
    b0 = *(const b8*)(Bb + boff + 2048);
    b1 = *(const b8*)(Bb + boff + 3072);
    if (st) {
      STG(BT, goffB, stB, qo, kn);
      VMC4;
    } else {
      VMC0;
    }
    BAR();
    __builtin_amdgcn_s_setprio(1);
#pragma unroll
    for (int i = 0; i < 8; i++) {
      acc[i][2] = __builtin_amdgcn_mfma_f32_16x16x32_bf16(a[i], b0, acc[i][2], 0, 0, 0);
      acc[i][3] = __builtin_amdgcn_mfma_f32_16x16x32_bf16(a[i], b1, acc[i][3], 0, 0, 0);
    }
    __builtin_amdgcn_s_setprio(0);
    BAR();
    // ---- P3 ----
#pragma unroll
    for (int i = 0; i < 8; i++) a[i] = *(const b8*)(Ab + 16384 + aoff + i * 1024);
    b0 = *(const b8*)(Bb + 16384 + boff);
    b1 = *(const b8*)(Bb + 16384 + boff + 1024);
    if (st) STG(A, goffA, stA, qo + 16384, kn + 32);
    BAR();
    __builtin_amdgcn_s_setprio(1);
#pragma unroll
    for (int i = 0; i < 8; i++) {
      acc[i][0] = __builtin_amdgcn_mfma_f32_16x16x32_bf16(a[i], b0, acc[i][0], 0, 0, 0);
      acc[i][1] = __builtin_amdgcn_mfma_f32_16x16x32_bf16(a[i], b1, acc[i][1], 0, 0, 0);
    }
    __builtin_amdgcn_s_setprio(0);
    BAR();
    // ---- P4 ----
    b0 = *(const b8*)(Bb + 16384 + boff + 2048);
    b1 = *(const b8*)(Bb + 16384 + boff + 3072);
    if (st) {
      STG(BT, goffB, stB, qo + 16384, kn + 32);
      VMC4;
    } else {
      VMC0;
    }
    BAR();
    __builtin_amdgcn_s_setprio(1);
#pragma unroll
    for (int i = 0; i < 8; i++) {
      acc[i][2] = __builtin_amdgcn_mfma_f32_16x16x32_bf16(a[i], b0, acc[i][2], 0, 0, 0);
      acc[i][3] = __builtin_amdgcn_mfma_f32_16x16x32_bf16(a[i], b1, acc[i][3], 0, 0, 0);
    }
    __builtin_amdgcn_s_setprio(0);
    BAR();
  }
#undef STG

#pragma unroll
  for (int j = 0; j < 4; j++) {
    int n = n0 + wn * 64 + j * 16 + l16;
    float bv = bias[n];
#pragma unroll
    for (int i = 0; i < 8; i++) {
#pragma unroll
      for (int r = 0; r < 4; r++) {
        int m = m0 + wm * 128 + i * 16 + q4 * 4 + r;
        C[(long)m * LDC + n] = __float2bfloat16(acc[i][j][r] + bv);
      }
    }
  }
}

// ================= bf16 MFMA GEMM: C = A(MxK) @ BT(NxK)^T =================
// 128x128 tile, 4 waves, 4x4 of 16x16x32 frags/wave, BK=32.
// Staging via global_load_lds width=16; linear LDS [128][32] per tile.
// EPI: 0=plain (OBF/RELU), 2=H-update, 3=split-K f32 atomicAdd, 4=transposed bf16.
template <int OBF, int RELU, int BIAS, int EPI>
__global__ __launch_bounds__(256, 2) void bgemm(
    const __hip_bfloat16* __restrict__ A, const __hip_bfloat16* __restrict__ BT,
    void* __restrict__ Cv, const float* __restrict__ bias,
    float* __restrict__ auxf, __hip_bfloat16* __restrict__ auxb,
    int K, int lda, int ldb, int ldc,
    int zshift, int zmask, long sA1, long sA2, long sB1, long sB2, long sC,
    int czdiv) {
  __shared__ __hip_bfloat16 Asp[128 * 32];
  __shared__ __hip_bfloat16 Bsp[128 * 32];
  int z = blockIdx.z;
  A += (long)(z >> zshift) * sA1 + (long)(z & zmask) * sA2;
  BT += (long)(z >> zshift) * sB1 + (long)(z & zmask) * sB2;
  int tid = threadIdx.x;
  int lane = tid & 63, w = tid >> 6;
  int wr = w >> 1, wc = w & 1;
  int l16 = lane & 15, q = lane >> 4;
  int m0 = blockIdx.y << 7, n0 = blockIdx.x << 7;

  int fm = tid >> 2, fq = tid & 3;
  const __hip_bfloat16* Ap0 = A + (long)(m0 + fm) * lda + fq * 8;
  const __hip_bfloat16* Ap1 = A + (long)(m0 + fm + 64) * lda + fq * 8;
  const __hip_bfloat16* Bp0 = BT + (long)(n0 + fm) * ldb + fq * 8;
  const __hip_bfloat16* Bp1 = BT + (long)(n0 + fm + 64) * ldb + fq * 8;
  char* Aw0 = (char*)Asp + (w << 10);
  char* Aw1 = (char*)Asp + 4096 + (w << 10);
  char* Bw0 = (char*)Bsp + (w << 10);
  char* Bw1 = (char*)Bsp + 4096 + (w << 10);

  f4 acc[4][4];
#pragma unroll
  for (int i = 0; i < 4; i++)
#pragma unroll
    for (int j = 0; j < 4; j++) acc[i][j] = (f4){0.f, 0.f, 0.f, 0.f};

  for (int k0 = 0; k0 < K; k0 += 32) {
    GLDS(Ap0 + k0, Aw0);
    GLDS(Ap1 + k0, Aw1);
    GLDS(Bp0 + k0, Bw0);
    GLDS(Bp1 + k0, Bw1);
    __syncthreads();
    b8 af[4], bf[4];
#pragma unroll
    for (int i = 0; i < 4; i++)
      af[i] = *(const b8*)&Asp[(wr * 64 + i * 16 + l16) * 32 + q * 8];
#pragma unroll
    for (int j = 0; j < 4; j++)
      bf[j] = *(const b8*)&Bsp[(wc * 64 + j * 16 + l16) * 32 + q * 8];
#pragma unroll
    for (int i = 0; i < 4; i++)
#pragma unroll
      for (int j = 0; j < 4; j++)
        acc[i][j] = __builtin_amdgcn_mfma_f32_16x16x32_bf16(af[i], bf[j], acc[i][j], 0, 0, 0);
    __syncthreads();
  }
  if (EPI == 4) {
#pragma unroll
    for (int j = 0; j < 4; j++) {
      int n = n0 + wc * 64 + j * 16 + l16;
#pragma unroll
      for (int i = 0; i < 4; i++) {
        int m = m0 + wr * 64 + i * 16 + (q << 2);
        __hip_bfloat16 t4[4];
#pragma unroll
        for (int r = 0; r < 4; r++) t4[r] = __float2bfloat16(acc[i][j][r]);
        long bidx = (long)(m >> 8) * sC + (long)n * cL + (m & 255);
        *(uint2*)&((__hip_bfloat16*)Cv)[bidx] = *(uint2*)t4;
      }
    }
    return;
  }
  long cz = (long)(z >> czdiv) * sC;
#pragma unroll
  for (int j = 0; j < 4; j++) {
    int n = n0 + wc * 64 + j * 16 + l16;
    float bv = BIAS ? bias[n] : 0.f;
#pragma unroll
    for (int i = 0; i < 4; i++) {
#pragma unroll
      for (int r = 0; r < 4; r++) {
        int m = m0 + wr * 64 + i * 16 + q * 4 + r;
        long idx = cz + (long)m * ldc + n;
        float v = acc[i][j][r] + bv;
        if (EPI == 0) {
          if (RELU) v = fmaxf(v, 0.f);
          if (OBF)
            ((__hip_bfloat16*)Cv)[idx] = __float2bfloat16(v);
          else
            ((float*)Cv)[idx] = v;
        } else if (EPI == 3) {
          atomicAdd(&((float*)Cv)[idx], v);
        } else {
          v = fmaxf(v, 0.f);
          float h = auxf[idx];
          float g = sigf(h);
          float o = h + g * (v - h);
          auxf[idx] = o;
          auxb[idx] = __float2bfloat16(o);
        }
      }
    }
  }
}

// ======== dual adjacency GEMM: Isem/Ilat share BT; fused I_com epilogue ========
__global__ __launch_bounds__(256, 2) void bgemm_dual(
    const __hip_bfloat16* __restrict__ A1g, const __hip_bfloat16* __restrict__ A2g,
    const __hip_bfloat16* __restrict__ BTg, float* __restrict__ IsemF,
    __hip_bfloat16* __restrict__ Icb, const float* __restrict__ bias,
    int write_isem) {
  __shared__ __hip_bfloat16 A1sp[128 * 32];
  __shared__ __hip_bfloat16 A2sp[128 * 32];
  __shared__ __hip_bfloat16 Bsp[128 * 32];
  int z = blockIdx.z;
  const __hip_bfloat16* A1 = A1g + (long)z * cLL;
  const __hip_bfloat16* A2 = A2g + (long)z * cLL;
  const __hip_bfloat16* BT = BTg + (long)z * cLD;
  int tid = threadIdx.x;
  int lane = tid & 63, w = tid >> 6;
  int wr = w >> 1, wc = w & 1;
  int l16 = lane & 15, q = lane >> 4;
  int m0 = blockIdx.y << 7, n0 = blockIdx.x << 7;

  int fm = tid >> 2, fq = tid & 3;
  const __hip_bfloat16* A1p0 = A1 + (long)(m0 + fm) * cL + fq * 8;
  const __hip_bfloat16* A1p1 = A1p0 + 64L * cL;
  const __hip_bfloat16* A2p0 = A2 + (long)(m0 + fm) * cL + fq * 8;
  const __hip_bfloat16* A2p1 = A2p0 + 64L * cL;
  const __hip_bfloat16* Bp0 = BT + (long)(n0 + fm) * cL + fq * 8;
  const __hip_bfloat16* Bp1 = Bp0 + 64L * cL;
  char* w10 = (char*)A1sp + (w << 10);
  char* w11 = (char*)A1sp + 4096 + (w << 10);
  char* w20 = (char*)A2sp + (w << 10);
  char* w21 = (char*)A2sp + 4096 + (w << 10);
  char* wb0 = (char*)Bsp + (w << 10);
  char* wb1 = (char*)Bsp + 4096 + (w << 10);

  f4 ac1[4][4], ac2[4][4];
#pragma unroll
  for (int i = 0; i < 4; i++)
#pragma unroll
    for (int j = 0; j < 4; j++) {
      ac1[i][j] = (f4){0.f, 0.f, 0.f, 0.f};
      ac2[i][j] = (f4){0.f, 0.f, 0.f, 0.f};
    }

  for (int k0 = 0; k0 < cL; k0 += 32) {
    GLDS(A1p0 + k0, w10);
    GLDS(A1p1 + k0, w11);
    GLDS(A2p0 + k0, w20);
    GLDS(A2p1 + k0, w21);
    GLDS(Bp0 + k0, wb0);
    GLDS(Bp1 + k0, wb1);
    __syncthreads();
    b8 a1f[4], a2f[4], bf[4];
#pragma unroll
    for (int i = 0; i < 4; i++) {
      a1f[i] = *(const b8*)&A1sp[(wr * 64 + i * 16 + l16) * 32 + q * 8];
      a2f[i] = *(const b8*)&A2sp[(wr * 64 + i * 16 + l16) * 32 + q * 8];
    }
#pragma unroll
    for (int j = 0; j < 4; j++)
      bf[j] = *(const b8*)&Bsp[(wc * 64 + j * 16 + l16) * 32 + q * 8];
#pragma unroll
    for (int i = 0; i < 4; i++)
#pragma unroll
      for (int j = 0; j < 4; j++) {
        ac1[i][j] = __builtin_amdgcn_mfma_f32_16x16x32_bf16(a1f[i], bf[j], ac1[i][j], 0, 0, 0);
        ac2[i][j] = __builtin_amdgcn_mfma_f32_16x16x32_bf16(a2f[i], bf[j], ac2[i][j], 0, 0, 0);
      }
    __syncthreads();
  }
  long cz = (long)z * cLD;
#pragma unroll
  for (int j = 0; j < 4; j++) {
    int n = n0 + wc * 64 + j * 16 + l16;
    float bv = bias[n];
#pragma unroll
    for (int i = 0; i < 4; i++) {
#pragma unroll
      for (int r = 0; r < 4; r++) {
        int m = m0 + wr * 64 + i * 16 + q * 4 + r;
        long idx = cz + (long)m * cD + n;
        float is = ac1[i][j][r] + bv;
        float il = ac2[i][j][r] + bv;
        float g = 0.5f * sigf(il);
        Icb[idx] = __float2bfloat16(is + g * (il - is));
        if (write_isem) IsemF[idx] = is;
      }
    }
  }
}

// ---------------- 7 weight convert+transpose in one dispatch ----------------
__global__ void k_wconv7(const float* __restrict__ s0, const float* __restrict__ s1,
                         const float* __restrict__ s2, const float* __restrict__ s3,
                         const float* __restrict__ s4, const float* __restrict__ s5,
                         const float* __restrict__ s6, __hip_bfloat16* __restrict__ dst) {
  const float* srcs[7] = {s0, s1, s2, s3, s4, s5, s6};
  const float* src = srcs[blockIdx.z];
  __hip_bfloat16* d = dst + (long)blockIdx.z * cD * cD;
  __shared__ float t[32][33];
  int k0 = blockIdx.x * 32, n0 = blockIdx.y * 32;
  int tx = threadIdx.x, ty = threadIdx.y;
#pragma unroll
  for (int i = 0; i < 32; i += 8) t[ty + i][tx] = src[(long)(k0 + ty + i) * cD + n0 + tx];
  __syncthreads();
#pragma unroll
  for (int i = 0; i < 32; i += 8)
    d[(long)(n0 + ty + i) * cD + k0 + tx] = __float2bfloat16(t[tx][ty + i]);
}

// ---------------- embedding + layernorm + fused root dot ----------------
__global__ __launch_bounds__(256) void k_gcnin(
    const int* __restrict__ tbi, const int* __restrict__ bsi,
    const float* __restrict__ tok, const float* __restrict__ seg,
    const float* __restrict__ ln_a, const float* __restrict__ ln_b,
    const float* __restrict__ root_w,
    float* __restrict__ gcn_in, __hip_bfloat16* __restrict__ gib,
    float* __restrict__ x64, float* __restrict__ e1) {
  long bl = blockIdx.x;
  int t = tbi[bl], s = bsi[bl];
  const float* tr = tok + (long)t * cD;
  const float* sr = seg + (long)s * cD;
  float x[3];
  float ls = 0.f;
#pragma unroll
  for (int i = 0; i < 3; i++) {
    int d = threadIdx.x + (i << 8);
    x[i] = tr[d] + sr[d];
    ls += x[i];
  }
  if ((bl & 255) == 0) {
#pragma unroll
    for (int i = 0; i < 3; i++) x64[(bl >> 8) * cD + threadIdx.x + (i << 8)] = x[i];
  }
  float mean = blockSum(ls) * (1.f / 768.f);
  float lv = 0.f;
#pragma unroll
  for (int i = 0; i < 3; i++) { float c = x[i] - mean; lv += c * c; }
  float var = blockSum(lv) * (1.f / 767.f);
  float inv = 1.f / (sqrtf(var) + 1e-6f);
  float rdot = 0.f;
#pragma unroll
  for (int i = 0; i < 3; i++) {
    int d = threadIdx.x + (i << 8);
    float v = ln_a[d] * (x[i] - mean) * inv + ln_b[d];
    gcn_in[bl * cD + d] = v;
    gib[bl * cD + d] = __float2bfloat16(v);
    rdot += v * root_w[d];
  }
  float tot = blockSum(rdot);
  if (threadIdx.x == 0) e1[bl] = tot;
}

// ---------------- pooled GEMV partials ----------------
__global__ __launch_bounds__(256) void k_pool1(
    const float* __restrict__ x64, const float* __restrict__ pw,
    float* __restrict__ pacc) {
  __shared__ float pws[48][256];
  __shared__ float xs[16][48];
  int i0 = blockIdx.x * 48, j0 = blockIdx.y * 256, b0 = blockIdx.z * 16;
  for (int r = 0; r < 48; r++) pws[r][threadIdx.x] = pw[(long)(i0 + r) * cD + j0 + threadIdx.x];
  for (int idx = threadIdx.x; idx < 16 * 48; idx += 256)
    xs[idx / 48][idx % 48] = x64[(long)(b0 + idx / 48) * cD + i0 + idx % 48];
  __syncthreads();
  int j = threadIdx.x;
  for (int b = 0; b < 16; b++) {
    float acc = 0.f;
#pragma unroll 8
    for (int i = 0; i < 48; i++) acc += xs[b][i] * pws[i][j];
    atomicAdd(&pacc[(long)(b0 + b) * cD + j0 + j], acc);
  }
}
__global__ __launch_bounds__(256) void k_pool2(
    const float* __restrict__ pacc, const float* __restrict__ pb,
    float* __restrict__ pooled) {
  int b = blockIdx.x;
#pragma unroll
  for (int c = 0; c < 3; c++) {
    int j = (c << 8) + threadIdx.x;
    pooled[(long)b * cD + j] = tanhf(pacc[(long)b * cD + j] + pb[j]);
  }
}

// ---------------- dep LUT ----------------
__global__ __launch_bounds__(256) void k_s45(
    const float* __restrict__ dep_emb, const float* __restrict__ fc1w,
    const float* __restrict__ fc1b, const float* __restrict__ fc2w,
    const float* __restrict__ fc2b, float* __restrict__ s45) {
  int t = blockIdx.x;
  __shared__ float e[300];
  for (int i = threadIdx.x; i < 300; i += 256) e[i] = dep_emb[t * 300 + i];
  __syncthreads();
  int j = threadIdx.x;
  float h = fc1b[j];
  for (int i = 0; i < 300; i++) h += e[i] * fc1w[i * 256 + j];
  h = fmaxf(h, 0.f);
  float tot = blockSum(h * fc2w[j]);
  if (threadIdx.x == 0) s45[t] = tot + fc2b[0];
}

__global__ __launch_bounds__(256) void k_depfeat(
    const int* __restrict__ ori, const float* __restrict__ src_mask,
    const float* __restrict__ s45, float* __restrict__ dep_feat) {
  int b = blockIdx.x, l = threadIdx.x;
  float smv = (l == 0) ? 1.f : src_mask[b * cL + l];
  float sc = s45[ori[b * cL + l]] * smv + (1.f - smv) * (-1e30f);
  float mx = blockMax(sc);
  float ex = expf(sc - mx);
  float sum = blockSum(ex);
  dep_feat[b * cL + l] = ex / sum;
}

// ---------------- bias concat for fused projection ----------------
__global__ void k_bcat(const float* __restrict__ a, const float* __restrict__ b,
                       const float* __restrict__ c, const float* __restrict__ d,
                       float* __restrict__ o) {
  int i = blockIdx.x * 256 + threadIdx.x;
  float v = (i < 768) ? a[i] : (i < 1536) ? b[i - 768] : (i < 2304) ? c[i - 1536] : d[i - 2304];
  o[i] = v;
}

// ---------------- adj_ag softmax (bf16 scores in) ----------------
__global__ __launch_bounds__(256) void k_adjag_sm(
    const __hip_bfloat16* __restrict__ scores, const float* __restrict__ src_mask,
    __hip_bfloat16* __restrict__ adjag) {
  int b = blockIdx.x >> 8, i = blockIdx.x & 255;
  int tid = threadIdx.x, wave = tid >> 6, lane = tid & 63;
  __shared__ float accs[4][256];
  const float scale = 1.f / (sqrtf(96.f) + 1e-9f);
  float smj[4], acc[4];
#pragma unroll
  for (int c = 0; c < 4; c++) {
    int j = c * 64 + lane;
    smj[c] = (j == 0) ? 1.f : src_mask[b * cL + j];
    acc[c] = 0.f;
  }
  for (int hh = 0; hh < 2; hh++) {
    int h = wave * 2 + hh;
    const __hip_bfloat16* row = scores + (((long)(b * 8 + h)) * cL + i) * cL;
    float s[4], m = -1e30f;
#pragma unroll
    for (int c = 0; c < 4; c++) {
      s[c] = (smj[c] == 0.f) ? -1e9f : __bfloat162float(row[c * 64 + lane]) * scale;
      m = fmaxf(m, s[c]);
    }
    m = wmax_all(m);
    float es = 0.f;
#pragma unroll
    for (int c = 0; c < 4; c++) { s[c] = expf(s[c] - m); es += s[c]; }
    es = wsum_all(es);
    float inv = 1.f / es;
#pragma unroll
    for (int c = 0; c < 4; c++) acc[c] += s[c] * inv;
  }
#pragma unroll
  for (int c = 0; c < 4; c++) accs[wave][c * 64 + lane] = acc[c];
  __syncthreads();
  int j = tid;
  float tot = accs[0][j] + accs[1][j] + accs[2][j] + accs[3][j];
  float smi = (i == 0) ? 1.f : src_mask[b * cL + i];
  float v = (j == i) ? 1.f : tot * 0.125f;
  adjag[((long)b * cL + i) * cL + j] = __float2bfloat16(v * smi);
}

// ---------------- adj_latent softmax + inlined dep_adj ----------------
__global__ __launch_bounds__(256) void k_adjlat_sm(
    const float* __restrict__ latsc, const int* __restrict__ head,
    const float* __restrict__ df, const float* __restrict__ src_mask,
    __hip_bfloat16* __restrict__ adjlat) {
  int b = blockIdx.x >> 8, i = blockIdx.x & 255;
  int j = threadIdx.x;
  float smj = (j == 0) ? 1.f : src_mask[b * cL + j];
  float dep = 1.f;
  if (j >= 1 && head[b * cL + j - 1] == i) dep = df[b * cL + j - 1];
  if (i >= 1 && j == head[b * cL + i - 1]) dep = df[b * cL + i - 1];
  float s = latsc[((long)b * cL + i) * cL + j] * (1.f / sqrtf(768.f)) +
            dep + (1.f - smj) * (-10000.f);
  float mx = blockMax(s);
  float ex = expf(s - mx);
  float sum = blockSum(ex);
  float p = ex / sum;
  float smi = (i == 0) ? 1.f : src_mask[b * cL + i];
  adjlat[((long)b * cL + i) * cL + j] = __float2bfloat16(((j == i) ? 1.f : p) * smi);
}

// ---------------- wave-per-row dot ----------------
__global__ __launch_bounds__(256) void k_rowdot(
    const float* __restrict__ X, const float* __restrict__ w, long wstride,
    float* __restrict__ e) {
  int r = blockIdx.x * 4 + (threadIdx.x >> 6);
  int lane = threadIdx.x & 63;
  const float4* row = (const float4*)(X + (long)r * cD);
  const float4* wp = (const float4*)(w + (long)(r >> 8) * wstride);
  float s = 0.f;
#pragma unroll
  for (int c = 0; c < 3; c++) {
    int idx = c * 64 + lane;
    float4 a = row[idx], b = wp[idx];
    s += a.x * b.x + a.y * b.y + a.z * b.z + a.w * b.w;
  }
  s = wsum(s);
  if (lane == 0) e[r] = s;
}

// ---------------- root loss ----------------
__global__ __launch_bounds__(256) void k_root2(
    const float* __restrict__ e1, const float* __restrict__ src_mask,
    const float* __restrict__ aspect_mask, float* __restrict__ out_loss) {
  int b = blockIdx.x, l = threadIdx.x;
  float r = e1[b * cL + l];
  float smv = (l == 0) ? 1.f : src_mask[b * cL + l];
  float sc = r * smv + (1.f - smv) * (-1e30f);
  float mx = blockMax(sc);
  float ex = expf(sc - mx);
  float sum = blockSum(ex);
  float p = ex / sum;
  float tot = blockSum(p * aspect_mask[b * cL + l]);
  if (l == 0) atomicAdd(out_loss, -logf(tot + 1e-9f) * (1.f / 64.f));
}

// ---------------- lexicon loss ----------------
__global__ __launch_bounds__(256) void k_lex2(
    const float* __restrict__ e2, const float* __restrict__ src_mask,
    const float* __restrict__ lex, float* __restrict__ out_loss) {
  int b = blockIdx.x, l = threadIdx.x;
  float e = e2[b * cL + l];
  float mx = blockMax(e);
  float ex = expf(e - mx);
  float sum = blockSum(ex);
  float mult = (l == 0) ? 0.f : src_mask[b * cL + l];
  float lw = ex / sum * 50.f * mult;
  float d2 = lw - lex[b * cL + l];
  float tot = blockSum(d2 * d2);
  if (l == 0) atomicAdd(out_loss, tot * (1.f / (64.f * 256.f)));
}

// ---------------- hlsum partials ----------------
__global__ __launch_bounds__(256) void k_hl(
    const float* __restrict__ H, const float* __restrict__ src_mask,
    float* __restrict__ hlsum) {
  int b = blockIdx.z, d = (blockIdx.y << 8) + threadIdx.x, l0 = blockIdx.x * 32;
  float acc = 0.f;
  for (int l = l0; l < l0 + 32; l++) {
    float smv = (l == 0) ? 1.f : src_mask[b * cL + l];
    acc += H[((long)b * cL + l) * cD + d] * smv;
  }
  atomicAdd(&hlsum[(long)b * cD + d], acc);
}

// ---------------- attn weights + asum ----------------
__global__ __launch_bounds__(256) void k_attnw(
    const float* __restrict__ sraw, const float* __restrict__ src_mask,
    const float* __restrict__ am, float* __restrict__ wgt, float* __restrict__ asum) {
  int b = blockIdx.x, k = threadIdx.x;
  float smk = (k == 0) ? 1.f : src_mask[b * cL + k];
  float s = sraw[b * cL + k] * smk * 0.001f;
  float mx = blockMax(s);
  float ex = expf(s - mx);
  float sum = blockSum(ex);
  wgt[b * cL + k] = ex / sum;
  float a = blockSum(am[b * cL + k]);
  if (k == 0) asum[b] = a;
}

// ---------------- fused outputs+sempool partials ----------------
__global__ __launch_bounds__(256) void k_wsum(
    const float* __restrict__ Isem, const float* __restrict__ wgt,
    const float* __restrict__ am, float* __restrict__ outputs,
    float* __restrict__ sempool) {
  int b = blockIdx.z, d = (blockIdx.y << 8) + threadIdx.x, l0 = blockIdx.x * 32;
  float accO = 0.f, accS = 0.f;
  for (int l = l0; l < l0 + 32; l++) {
    float v = Isem[((long)b * cL + l) * cD + d];
    accO += wgt[b * cL + l] * v;
    accS += am[b * cL + l] * v;
  }
  atomicAdd(&outputs[(long)b * cD + d], accO);
  atomicAdd(&sempool[(long)b * cD + d], accS);
}

// ---------------- logits ----------------
__global__ __launch_bounds__(256) void k_logits(
    const float* __restrict__ outputs, const float* __restrict__ sempool,
    const float* __restrict__ pooled, const float* __restrict__ asum,
    const float* __restrict__ cw, const float* __restrict__ cb,
    float* __restrict__ out) {
  int b = blockIdx.x;
  float inv = 1.f / (asum[b] + 1e-9f);
  float a0 = 0.f, a1 = 0.f, a2 = 0.f;
  for (int i = threadIdx.x; i < 3 * cD; i += 256) {
    float f = (i < cD) ? outputs[(long)b * cD + i]
              : (i < 2 * cD) ? sempool[(long)b * cD + i - cD] * inv
                             : pooled[(long)b * cD + i - 2 * cD];
    a0 += f * cw[i * 3 + 0];
    a1 += f * cw[i * 3 + 1];
    a2 += f * cw[i * 3 + 2];
  }
  a0 = blockSum(a0);
  a1 = blockSum(a1);
  a2 = blockSum(a2);
  if (threadIdx.x == 0) {
    out[b * 3 + 0] = a0 + cb[0];
    out[b * 3 + 1] = a1 + cb[1];
    out[b * 3 + 2] = a2 + cb[2];
  }
}

extern "C" void kernel_launch(void* const* d_in, const int* in_sizes, int n_in,
                              void* d_out, int out_size, void* d_ws, size_t ws_size,
                              hipStream_t stream) {
  const int* tbi = (const int*)d_in[0];
  const int* bsi = (const int*)d_in[1];
  const float* src_mask = (const float*)d_in[3];
  const float* aspect_mask = (const float*)d_in[4];
  const float* lex = (const float*)d_in[5];
  const int* ori = (const int*)d_in[6];
  const int* head = (const int*)d_in[7];
  const float* tok_emb = (const float*)d_in[8];
  const float* seg_emb = (const float*)d_in[9];
  const float* pool_w = (const float*)d_in[10];
  const float* pool_b = (const float*)d_in[11];
  const float* ln_a = (const float*)d_in[12];
  const float* ln_b = (const float*)d_in[13];
  const float* dep_emb = (const float*)d_in[14];
  const float* fc1_w = (const float*)d_in[15];
  const float* fc1_b = (const float*)d_in[16];
  const float* fc2_w = (const float*)d_in[17];
  const float* fc2_b = (const float*)d_in[18];
  const float* aq_w = (const float*)d_in[19];
  const float* aq_b = (const float*)d_in[20];
  const float* ak_w = (const float*)d_in[21];
  const float* ak_b = (const float*)d_in[22];
  const float* lq_w = (const float*)d_in[23];
  const float* lq_b = (const float*)d_in[24];
  const float* lk_w = (const float*)d_in[25];
  const float* lk_b = (const float*)d_in[26];
  const float* root_w = (const float*)d_in[27];
  const float* gcn_w = (const float*)d_in[28];
  const float* gcn_b = (const float*)d_in[29];
  const float* fc3_w = (const float*)d_in[30];
  const float* fc3_b = (const float*)d_in[31];
  const float* cls_w = (const float*)d_in[32];
  const float* cls_b = (const float*)d_in[33];
  const float* vlin_w = (const float*)d_in[34];

  float* out = (float*)d_out;
  float* ws = (float*)d_ws;
  // fp32 region
  float* gcnH = ws;            // BLD (gcn_in -> H_l)
  float* Isem = gcnH + BLD;    // BLD  (also latsc f32 alias pre-loop)
  float* depfeat = Isem + BLD;         // B*L
  float* s45 = depfeat + cB * cL;      // 64
  float* pooled = s45 + 64;            // B*D
  float* x64 = pooled + cB * cD;       // B*D
  float* hlsum = x64 + cB * cD;        // B*D  --- zeroed region start
  float* outputs = hlsum + cB * cD;    // B*D
  float* sempool = outputs + cB * cD;  // B*D
  float* pacc = sempool + cB * cD;     // B*D  --- zeroed region end
  float* e1 = pacc + cB * cD;          // B*L
  float* e2 = e1 + cB * cL;            // B*L
  float* sraw = e2 + cB * cL;          // B*L
  float* wgt = sraw + cB * cL;         // B*L
  float* asum = wgt + cB * cL;         // 64
  float* catb = asum + 64;             // 3072
  float* latsc = Isem;                 // BLL f32 alias (dead until GCN loop)
  // bf16 region
  __hip_bfloat16* gib = (__hip_bfloat16*)(catb + 3072);  // BLD
  __hip_bfloat16* qkb = gib + BLD;             // 4*BLD (q|k|q2|k2, ldc=3072)
  __hip_bfloat16* scores = qkb + 4 * BLD;      // 8*BLL
  __hip_bfloat16* adjag_b = scores + 8 * BLL;  // BLL
  __hip_bfloat16* adjlat_b = adjag_b + BLL;    // BLL
  __hip_bfloat16* wbt = adjlat_b + BLL;        // 7*D*D
  // aliases
  __hip_bfloat16* HWbT = qkb + BLD;     // BLD (HW^T, written directly by EPI=4)
  __hip_bfloat16* Icb = qkb + 2 * BLD;  // BLD

  hipMemsetAsync((char*)d_out + 192 * sizeof(float), 0, 2 * sizeof(float), stream);
  hipMemsetAsync(hlsum, 0, 4 * cB * cD * sizeof(float), stream);
  hipMemsetAsync(latsc, 0, BLL * sizeof(float), stream);  // split-K accumulator

  // ---- prologue ----
  k_gcnin<<<cB * cL, 256, 0, stream>>>(tbi, bsi, tok_emb, seg_emb, ln_a, ln_b,
                                       root_w, gcnH, gib, x64, e1);
  k_s45<<<45, 256, 0, stream>>>(dep_emb, fc1_w, fc1_b, fc2_w, fc2_b, s45);
  k_depfeat<<<cB, 256, 0, stream>>>(ori, src_mask, s45, depfeat);
  k_pool1<<<dim3(16, 3, 4), 256, 0, stream>>>(x64, pool_w, pacc);
  k_pool2<<<cB, 256, 0, stream>>>(pacc, pool_b, pooled);
  k_bcat<<<12, 256, 0, stream>>>(aq_b, ak_b, lq_b, lk_b, catb);
  k_wconv7<<<dim3(24, 24, 7), dim3(32, 8), 0, stream>>>(
      aq_w, ak_w, lq_w, lk_w, gcn_w, gcn_w + (long)cD * cD, fc3_w, wbt);

  const long DD = (long)cD * cD;
  const long LD = cLD, LL = cLL;
  const long LP = (long)cL * 3072;  // qkb batch stride

  // ---- fused 4-way projection: qkb = gib @ [aq|ak|lq|lk] + catb ----
  bgemm256<<<dim3(12, 64), 512, 0, stream>>>(gib, wbt, qkb, catb);

  // ---- head scores (bf16 out) + adj_ag softmax ----
  bgemm<1, 0, 0, 0><<<dim3(2, 2, cB * 8), 256, 0, stream>>>(
      qkb, qkb + 768, scores, nullptr, nullptr, nullptr,
      96, 3072, 3072, cL, 3, 7, LP, 96, LP, 96, LL, 0);
  k_adjag_sm<<<cB * cL, 256, 0, stream>>>(scores, src_mask, adjag_b);

  // ---- latent scores: split-K (2x384) f32 atomicAdd + adj_latent softmax ----
  bgemm<0, 0, 0, 3><<<dim3(2, 2, cB * 2), 256, 0, stream>>>(
      qkb + 1536, qkb + 2304, latsc, nullptr, nullptr, nullptr,
      384, 3072, 3072, cL, 1, 1, LP, 384, LP, 384, LL, 1);
  k_adjlat_sm<<<cB * cL, 256, 0, stream>>>(latsc, head, depfeat, src_mask, adjlat_b);

  // ---- root loss (e1 fused into k_gcnin) ----
  k_root2<<<cB, 256, 0, stream>>>(e1, src_mask, aspect_mask, out + 192);

  // ---- GCN loop ----
  for (int layer = 0; layer < 2; layer++) {
    const float* bb = gcn_b + (long)layer * cD;
    // HW^T = (H @ W)^T written directly (EPI=4), layout (b, d, l)
    bgemm<1, 0, 0, 4><<<dim3(6, 128, 1), 256, 0, stream>>>(
        gib, wbt + (4 + layer) * DD, HWbT, nullptr, nullptr, nullptr,
        cD, cD, cD, cD, 0, 0, 0, 0, 0, 0, LD, 0);
    // dual adjacency GEMM + fused I_com epilogue (writes Isem f32 on last layer)
    bgemm_dual<<<dim3(6, 2, cB), 256, 0, stream>>>(
        adjag_b, adjlat_b, HWbT, Isem, Icb, bb, layer == 1 ? 1 : 0);
    // fc3 GEMM with fused H-gate epilogue: updates gcnH (f32) + gib (bf16)
    bgemm<0, 1, 1, 2><<<dim3(6, 128, 1), 256, 0, stream>>>(
        Icb, wbt + 6 * DD, nullptr, fc3_b, gcnH, gib,
        cD, cD, cD, cD, 0, 0, 0, 0, 0, 0, 0, 0);
  }

  // ---- tail ----
  k_hl<<<dim3(8, 3, cB), 256, 0, stream>>>(gcnH, src_mask, hlsum);
  k_rowdot<<<cB * cL / 4, 256, 0, stream>>>(Isem, hlsum, cD, sraw);
  k_attnw<<<cB, 256, 0, stream>>>(sraw, src_mask, aspect_mask, wgt, asum);
  k_wsum<<<dim3(8, 3, cB), 256, 0, stream>>>(Isem, wgt, aspect_mask, outputs, sempool);
  k_logits<<<cB, 256, 0, stream>>>(outputs, sempool, pooled, asum, cls_w, cls_b, out);
  k_rowdot<<<cB * cL / 4, 256, 0, stream>>>(gcnH, vlin_w, 0, e2);
  k_lex2<<<cB, 256, 0, stream>>>(e2, src_mask, lex, out + 193);
}

// Round 4
// 807.036 us; speedup vs baseline: 1.1234x; 1.1201x over previous
//
#include <hip/hip_runtime.h>
#include <hip/hip_bf16.h>
#include <math.h>

#define DI __device__ __forceinline__

constexpr int cB = 64, cL = 256, cD = 768;
constexpr long BLD = (long)cB * cL * cD;   // 12,582,912
constexpr long BLL = (long)cB * cL * cL;   //  4,194,304
constexpr long cLL = (long)cL * cL;
constexpr long cLD = (long)cL * cD;

typedef __attribute__((ext_vector_type(8))) short b8;
typedef __attribute__((ext_vector_type(4))) float f4;

// async global->LDS, 16B per lane, dest = wave-uniform base + lane*16 (linear)
#define GLDS(g, l)                                                    \
  __builtin_amdgcn_global_load_lds(                                   \
      (const __attribute__((address_space(1))) void*)(g),             \
      (__attribute__((address_space(3))) void*)(l), 16, 0, 0)

// ---------------- reductions (wave64) ----------------
DI float wsum(float v) {
#pragma unroll
  for (int o = 32; o > 0; o >>= 1) v += __shfl_down(v, o, 64);
  return v;
}
DI float wsum_all(float v) {
#pragma unroll
  for (int m = 32; m > 0; m >>= 1) v += __shfl_xor(v, m, 64);
  return v;
}
DI float wmax_all(float v) {
#pragma unroll
  for (int m = 32; m > 0; m >>= 1) v = fmaxf(v, __shfl_xor(v, m, 64));
  return v;
}
DI float wmaxr(float v) {
#pragma unroll
  for (int o = 32; o > 0; o >>= 1) v = fmaxf(v, __shfl_down(v, o, 64));
  return v;
}
DI float blockSum(float v) {
  __shared__ float sh[4];
  v = wsum(v);
  __syncthreads();
  if ((threadIdx.x & 63) == 0) sh[threadIdx.x >> 6] = v;
  __syncthreads();
  return sh[0] + sh[1] + sh[2] + sh[3];
}
DI float blockMax(float v) {
  __shared__ float sh[4];
  v = wmaxr(v);
  __syncthreads();
  if ((threadIdx.x & 63) == 0) sh[threadIdx.x >> 6] = v;
  __syncthreads();
  return fmaxf(fmaxf(sh[0], sh[1]), fmaxf(sh[2], sh[3]));
}
DI float sigf(float x) { return 1.f / (1.f + expf(-x)); }

// ================= bf16 MFMA GEMM: C = A(MxK) @ BT(NxK)^T =================
// 128x128 tile, 4 waves, 4x4 of 16x16x32 frags/wave, BK=32.
// Staging via global_load_lds width=16; linear LDS [128][32] per tile.
// EPI: 0=plain (OBF/RELU), 2=H-update (gate vs bf16 H in auxb; optional f32 out),
//      4=transposed bf16 write (per-256-row batch).
template <int OBF, int RELU, int BIAS, int EPI>
__global__ __launch_bounds__(256, 2) void bgemm(
    const __hip_bfloat16* __restrict__ A, const __hip_bfloat16* __restrict__ BT,
    void* __restrict__ Cv, const float* __restrict__ bias,
    float* __restrict__ auxf, __hip_bfloat16* __restrict__ auxb,
    int K, int lda, int ldb, int ldc,
    int zshift, int zmask, long sA1, long sA2, long sB1, long sB2, long sC,
    int czdiv) {
  __shared__ __hip_bfloat16 Asp[128 * 32];
  __shared__ __hip_bfloat16 Bsp[128 * 32];
  int z = blockIdx.z;
  A += (long)(z >> zshift) * sA1 + (long)(z & zmask) * sA2;
  BT += (long)(z >> zshift) * sB1 + (long)(z & zmask) * sB2;
  int tid = threadIdx.x;
  int lane = tid & 63, w = tid >> 6;
  int wr = w >> 1, wc = w & 1;
  int l16 = lane & 15, q = lane >> 4;
  int m0 = blockIdx.y << 7, n0 = blockIdx.x << 7;

  int fm = tid >> 2, fq = tid & 3;
  const __hip_bfloat16* Ap0 = A + (long)(m0 + fm) * lda + fq * 8;
  const __hip_bfloat16* Ap1 = A + (long)(m0 + fm + 64) * lda + fq * 8;
  const __hip_bfloat16* Bp0 = BT + (long)(n0 + fm) * ldb + fq * 8;
  const __hip_bfloat16* Bp1 = BT + (long)(n0 + fm + 64) * ldb + fq * 8;
  char* Aw0 = (char*)Asp + (w << 10);
  char* Aw1 = (char*)Asp + 4096 + (w << 10);
  char* Bw0 = (char*)Bsp + (w << 10);
  char* Bw1 = (char*)Bsp + 4096 + (w << 10);

  f4 acc[4][4];
#pragma unroll
  for (int i = 0; i < 4; i++)
#pragma unroll
    for (int j = 0; j < 4; j++) acc[i][j] = (f4){0.f, 0.f, 0.f, 0.f};

  for (int k0 = 0; k0 < K; k0 += 32) {
    GLDS(Ap0 + k0, Aw0);
    GLDS(Ap1 + k0, Aw1);
    GLDS(Bp0 + k0, Bw0);
    GLDS(Bp1 + k0, Bw1);
    __syncthreads();
    b8 af[4], bf[4];
#pragma unroll
    for (int i = 0; i < 4; i++)
      af[i] = *(const b8*)&Asp[(wr * 64 + i * 16 + l16) * 32 + q * 8];
#pragma unroll
    for (int j = 0; j < 4; j++)
      bf[j] = *(const b8*)&Bsp[(wc * 64 + j * 16 + l16) * 32 + q * 8];
#pragma unroll
    for (int i = 0; i < 4; i++)
#pragma unroll
      for (int j = 0; j < 4; j++)
        acc[i][j] = __builtin_amdgcn_mfma_f32_16x16x32_bf16(af[i], bf[j], acc[i][j], 0, 0, 0);
    __syncthreads();
  }
  if (EPI == 4) {
#pragma unroll
    for (int j = 0; j < 4; j++) {
      int n = n0 + wc * 64 + j * 16 + l16;
#pragma unroll
      for (int i = 0; i < 4; i++) {
        int m = m0 + wr * 64 + i * 16 + (q << 2);
        __hip_bfloat16 t4[4];
#pragma unroll
        for (int r = 0; r < 4; r++) t4[r] = __float2bfloat16(acc[i][j][r]);
        long bidx = (long)(m >> 8) * sC + (long)n * cL + (m & 255);
        *(uint2*)&((__hip_bfloat16*)Cv)[bidx] = *(uint2*)t4;
      }
    }
    return;
  }
  long cz = (long)(z >> czdiv) * sC;
#pragma unroll
  for (int j = 0; j < 4; j++) {
    int n = n0 + wc * 64 + j * 16 + l16;
    float bv = BIAS ? bias[n] : 0.f;
#pragma unroll
    for (int i = 0; i < 4; i++) {
#pragma unroll
      for (int r = 0; r < 4; r++) {
        int m = m0 + wr * 64 + i * 16 + q * 4 + r;
        long idx = cz + (long)m * ldc + n;
        float v = acc[i][j][r] + bv;
        if (EPI == 0) {
          if (RELU) v = fmaxf(v, 0.f);
          if (OBF)
            ((__hip_bfloat16*)Cv)[idx] = __float2bfloat16(v);
          else
            ((float*)Cv)[idx] = v;
        } else {
          // EPI==2: v = Hout = relu(acc+bias); h = bf16 H (auxb);
          // H' = h + sig(h)*(Hout - h); write bf16 always, f32 only if auxf.
          v = fmaxf(v, 0.f);
          float h = __bfloat162float(auxb[idx]);
          float g = sigf(h);
          float o = h + g * (v - h);
          auxb[idx] = __float2bfloat16(o);
          if (auxf) auxf[idx] = o;
        }
      }
    }
  }
}

// ======== dual adjacency GEMM: Isem/Ilat share BT; fused I_com epilogue ========
__global__ __launch_bounds__(256, 2) void bgemm_dual(
    const __hip_bfloat16* __restrict__ A1g, const __hip_bfloat16* __restrict__ A2g,
    const __hip_bfloat16* __restrict__ BTg, float* __restrict__ IsemF,
    __hip_bfloat16* __restrict__ Icb, const float* __restrict__ bias,
    int write_isem) {
  __shared__ __hip_bfloat16 A1sp[128 * 32];
  __shared__ __hip_bfloat16 A2sp[128 * 32];
  __shared__ __hip_bfloat16 Bsp[128 * 32];
  int z = blockIdx.z;
  const __hip_bfloat16* A1 = A1g + (long)z * cLL;
  const __hip_bfloat16* A2 = A2g + (long)z * cLL;
  const __hip_bfloat16* BT = BTg + (long)z * cLD;
  int tid = threadIdx.x;
  int lane = tid & 63, w = tid >> 6;
  int wr = w >> 1, wc = w & 1;
  int l16 = lane & 15, q = lane >> 4;
  int m0 = blockIdx.y << 7, n0 = blockIdx.x << 7;

  int fm = tid >> 2, fq = tid & 3;
  const __hip_bfloat16* A1p0 = A1 + (long)(m0 + fm) * cL + fq * 8;
  const __hip_bfloat16* A1p1 = A1p0 + 64L * cL;
  const __hip_bfloat16* A2p0 = A2 + (long)(m0 + fm) * cL + fq * 8;
  const __hip_bfloat16* A2p1 = A2p0 + 64L * cL;
  const __hip_bfloat16* Bp0 = BT + (long)(n0 + fm) * cL + fq * 8;
  const __hip_bfloat16* Bp1 = Bp0 + 64L * cL;
  char* w10 = (char*)A1sp + (w << 10);
  char* w11 = (char*)A1sp + 4096 + (w << 10);
  char* w20 = (char*)A2sp + (w << 10);
  char* w21 = (char*)A2sp + 4096 + (w << 10);
  char* wb0 = (char*)Bsp + (w << 10);
  char* wb1 = (char*)Bsp + 4096 + (w << 10);

  f4 ac1[4][4], ac2[4][4];
#pragma unroll
  for (int i = 0; i < 4; i++)
#pragma unroll
    for (int j = 0; j < 4; j++) {
      ac1[i][j] = (f4){0.f, 0.f, 0.f, 0.f};
      ac2[i][j] = (f4){0.f, 0.f, 0.f, 0.f};
    }

  for (int k0 = 0; k0 < cL; k0 += 32) {
    GLDS(A1p0 + k0, w10);
    GLDS(A1p1 + k0, w11);
    GLDS(A2p0 + k0, w20);
    GLDS(A2p1 + k0, w21);
    GLDS(Bp0 + k0, wb0);
    GLDS(Bp1 + k0, wb1);
    __syncthreads();
    b8 a1f[4], a2f[4], bf[4];
#pragma unroll
    for (int i = 0; i < 4; i++) {
      a1f[i] = *(const b8*)&A1sp[(wr * 64 + i * 16 + l16) * 32 + q * 8];
      a2f[i] = *(const b8*)&A2sp[(wr * 64 + i * 16 + l16) * 32 + q * 8];
    }
#pragma unroll
    for (int j = 0; j < 4; j++)
      bf[j] = *(const b8*)&Bsp[(wc * 64 + j * 16 + l16) * 32 + q * 8];
#pragma unroll
    for (int i = 0; i < 4; i++)
#pragma unroll
      for (int j = 0; j < 4; j++) {
        ac1[i][j] = __builtin_amdgcn_mfma_f32_16x16x32_bf16(a1f[i], bf[j], ac1[i][j], 0, 0, 0);
        ac2[i][j] = __builtin_amdgcn_mfma_f32_16x16x32_bf16(a2f[i], bf[j], ac2[i][j], 0, 0, 0);
      }
    __syncthreads();
  }
  long cz = (long)z * cLD;
#pragma unroll
  for (int j = 0; j < 4; j++) {
    int n = n0 + wc * 64 + j * 16 + l16;
    float bv = bias[n];
#pragma unroll
    for (int i = 0; i < 4; i++) {
#pragma unroll
      for (int r = 0; r < 4; r++) {
        int m = m0 + wr * 64 + i * 16 + q * 4 + r;
        long idx = cz + (long)m * cD + n;
        float is = ac1[i][j][r] + bv;
        float il = ac2[i][j][r] + bv;
        float g = 0.5f * sigf(il);
        Icb[idx] = __float2bfloat16(is + g * (il - is));
        if (write_isem) IsemF[idx] = is;
      }
    }
  }
}

// ============ fused QK^T + mask(+dep) + row-softmax -> adjacency (bf16) ============
// NH=8: adj_ag = mean_h softmax(QK^T/sqrt(96), mask) from qkb cols [0|768)
// NH=1: adj_lat = softmax(Q2K2^T/sqrt(768) + dep_adj - mask*1e4) from cols [1536|2304)
// Block: 64 q-rows (blockIdx.x) x full 256 k-cols for batch b=blockIdx.y.
// 4 waves; wave w owns cols [w*64,(w+1)*64); per-head acc 4x4 frags of 16x16x32.
// Row stats: per-(i,r) j-fold + 16-lane shfl + cross-wave LDS reduce.
template <int NH>
__global__ __launch_bounds__(256, 2) void k_qkadj(
    const __hip_bfloat16* __restrict__ qkb, const float* __restrict__ src_mask,
    const int* __restrict__ headv, const float* __restrict__ df,
    __hip_bfloat16* __restrict__ outA) {
  constexpr int KH = (NH == 8) ? 96 : 768;
  constexpr int QOFF = (NH == 8) ? 0 : 1536;
  constexpr int KOFF = (NH == 8) ? 768 : 2304;
  const float scale = (NH == 8) ? (1.f / (sqrtf(96.f) + 1e-9f)) : (1.f / sqrtf(768.f));
  __shared__ __hip_bfloat16 Qs[64 * 32];   // 4 KB
  __shared__ __hip_bfloat16 Ks[256 * 32];  // 16 KB
  __shared__ float red[4][64];
  const int b = blockIdx.y, m0 = blockIdx.x << 6;
  const int tid = threadIdx.x, lane = tid & 63, w = tid >> 6;
  const int l16 = lane & 15, q = lane >> 4;
  const long rowbase = (long)b * cL;
  // staging: chunk = tid (Q, 4KB) / u*256+tid (K, 16KB); row=chunk>>2, c16=chunk&3
  const __hip_bfloat16* Qg = qkb + (rowbase + m0 + (tid >> 2)) * 3072 + (tid & 3) * 8 + QOFF;
  const __hip_bfloat16* Kg = qkb + (rowbase + (tid >> 2)) * 3072 + (tid & 3) * 8 + KOFF;
  char* qdst = (char*)Qs + (w << 10);

  float smj[4];
  int hcol[4];
  float dfc[4];
#pragma unroll
  for (int j = 0; j < 4; j++) {
    int col = w * 64 + j * 16 + l16;
    smj[j] = (col == 0) ? 1.f : src_mask[b * cL + col];
    if (NH == 1) {
      hcol[j] = (col >= 1) ? headv[b * cL + col - 1] : -1;
      dfc[j] = (col >= 1) ? df[b * cL + col - 1] : 0.f;
    }
  }
  float smi_[4][4];
  int hrow_[4][4];
  float dfr_[4][4];
#pragma unroll
  for (int i = 0; i < 4; i++)
#pragma unroll
    for (int r = 0; r < 4; r++) {
      int grow = m0 + i * 16 + q * 4 + r;
      smi_[i][r] = (grow == 0) ? 1.f : src_mask[b * cL + grow];
      if (NH == 1) {
        hrow_[i][r] = (grow >= 1) ? headv[b * cL + grow - 1] : -1;
        dfr_[i][r] = (grow >= 1) ? df[b * cL + grow - 1] : 0.f;
      }
    }

  f4 aag[4][4];
#pragma unroll
  for (int i = 0; i < 4; i++)
#pragma unroll
    for (int j = 0; j < 4; j++) aag[i][j] = (f4){0.f, 0.f, 0.f, 0.f};

  f4 sa[4][4];
  float inv_[4][4];
  for (int h = 0; h < NH; h++) {
    const int hk = h * 96;
#pragma unroll
    for (int i = 0; i < 4; i++)
#pragma unroll
      for (int j = 0; j < 4; j++) sa[i][j] = (f4){0.f, 0.f, 0.f, 0.f};
    for (int k0 = 0; k0 < KH; k0 += 32) {
      __syncthreads();  // previous readers of Qs/Ks (and red) done
      GLDS(Qg + hk + k0, qdst);
#pragma unroll
      for (int u = 0; u < 4; u++)
        GLDS(Kg + (long)u * 196608 + hk + k0, (char*)Ks + u * 4096 + (w << 10));
      __syncthreads();  // staged data visible (drains vmcnt)
      b8 af[4], bf[4];
#pragma unroll
      for (int i = 0; i < 4; i++)
        af[i] = *(const b8*)&Qs[(i * 16 + l16) * 32 + q * 8];
#pragma unroll
      for (int j = 0; j < 4; j++)
        bf[j] = *(const b8*)&Ks[(w * 64 + j * 16 + l16) * 32 + q * 8];
#pragma unroll
      for (int i = 0; i < 4; i++)
#pragma unroll
        for (int j = 0; j < 4; j++)
          sa[i][j] = __builtin_amdgcn_mfma_f32_16x16x32_bf16(af[i], bf[j], sa[i][j], 0, 0, 0);
    }
    // mask/scale (+dep for latent)
#pragma unroll
    for (int i = 0; i < 4; i++)
#pragma unroll
      for (int j = 0; j < 4; j++)
#pragma unroll
        for (int r = 0; r < 4; r++) {
          float raw = sa[i][j][r];
          float v;
          if (NH == 1) {
            int grow = m0 + i * 16 + q * 4 + r;
            int col = w * 64 + j * 16 + l16;
            float dep = 1.f;
            if (hcol[j] == grow) dep = dfc[j];
            if (col == hrow_[i][r]) dep = dfr_[i][r];
            v = raw * scale + dep + (1.f - smj[j]) * -10000.f;
          } else {
            v = (smj[j] == 0.f) ? -1e9f : raw * scale;
          }
          sa[i][j][r] = v;
        }
    // row max (j-fold -> 16-lane shfl -> cross-wave LDS)
    float rm_[4][4];
#pragma unroll
    for (int i = 0; i < 4; i++)
#pragma unroll
      for (int r = 0; r < 4; r++) {
        float m = fmaxf(fmaxf(sa[i][0][r], sa[i][1][r]), fmaxf(sa[i][2][r], sa[i][3][r]));
#pragma unroll
        for (int o = 1; o < 16; o <<= 1) m = fmaxf(m, __shfl_xor(m, o, 64));
        if (l16 == 0) red[w][i * 16 + q * 4 + r] = m;
        rm_[i][r] = m;
      }
    __syncthreads();
#pragma unroll
    for (int i = 0; i < 4; i++)
#pragma unroll
      for (int r = 0; r < 4; r++) {
        int lr = i * 16 + q * 4 + r;
        rm_[i][r] = fmaxf(fmaxf(red[0][lr], red[1][lr]), fmaxf(red[2][lr], red[3][lr]));
      }
    __syncthreads();  // all reads done before red reuse
    // exp + row sum
#pragma unroll
    for (int i = 0; i < 4; i++)
#pragma unroll
      for (int r = 0; r < 4; r++) {
        float s0 = 0.f;
#pragma unroll
        for (int j = 0; j < 4; j++) {
          float e = expf(sa[i][j][r] - rm_[i][r]);
          sa[i][j][r] = e;
          s0 += e;
        }
#pragma unroll
        for (int o = 1; o < 16; o <<= 1) s0 += __shfl_xor(s0, o, 64);
        if (l16 == 0) red[w][i * 16 + q * 4 + r] = s0;
      }
    __syncthreads();
#pragma unroll
    for (int i = 0; i < 4; i++)
#pragma unroll
      for (int r = 0; r < 4; r++) {
        int lr = i * 16 + q * 4 + r;
        inv_[i][r] = 1.f / (red[0][lr] + red[1][lr] + red[2][lr] + red[3][lr]);
      }
    if (NH == 8) {
#pragma unroll
      for (int i = 0; i < 4; i++)
#pragma unroll
        for (int j = 0; j < 4; j++)
#pragma unroll
          for (int r = 0; r < 4; r++) aag[i][j][r] += sa[i][j][r] * inv_[i][r];
    }
  }
  // write adjacency: diag=1, off-diag=p (mean over heads for NH=8), x smi
#pragma unroll
  for (int j = 0; j < 4; j++) {
    int col = w * 64 + j * 16 + l16;
#pragma unroll
    for (int i = 0; i < 4; i++)
#pragma unroll
      for (int r = 0; r < 4; r++) {
        int grow = m0 + i * 16 + q * 4 + r;
        float p = (NH == 8) ? aag[i][j][r] * 0.125f : sa[i][j][r] * inv_[i][r];
        float v = (col == grow) ? 1.f : p;
        outA[((long)b * cL + grow) * cL + col] = __float2bfloat16(v * smi_[i][r]);
      }
  }
}

// ---------------- 7 weight convert+transpose in one dispatch ----------------
__global__ void k_wconv7(const float* __restrict__ s0, const float* __restrict__ s1,
                         const float* __restrict__ s2, const float* __restrict__ s3,
                         const float* __restrict__ s4, const float* __restrict__ s5,
                         const float* __restrict__ s6, __hip_bfloat16* __restrict__ dst) {
  const float* srcs[7] = {s0, s1, s2, s3, s4, s5, s6};
  const float* src = srcs[blockIdx.z];
  __hip_bfloat16* d = dst + (long)blockIdx.z * cD * cD;
  __shared__ float t[32][33];
  int k0 = blockIdx.x * 32, n0 = blockIdx.y * 32;
  int tx = threadIdx.x, ty = threadIdx.y;
#pragma unroll
  for (int i = 0; i < 32; i += 8) t[ty + i][tx] = src[(long)(k0 + ty + i) * cD + n0 + tx];
  __syncthreads();
#pragma unroll
  for (int i = 0; i < 32; i += 8)
    d[(long)(n0 + ty + i) * cD + k0 + tx] = __float2bfloat16(t[tx][ty + i]);
}

// -------- embedding + layernorm + root dot, wave-per-row (bf16-only H out) --------
__global__ __launch_bounds__(256) void k_gcnin(
    const int* __restrict__ tbi, const int* __restrict__ bsi,
    const float* __restrict__ tok, const float* __restrict__ seg,
    const float* __restrict__ ln_a, const float* __restrict__ ln_b,
    const float* __restrict__ root_w, __hip_bfloat16* __restrict__ gib,
    float* __restrict__ x64, float* __restrict__ e1) {
  int wave = threadIdx.x >> 6, lane = threadIdx.x & 63;
  long bl = (long)blockIdx.x * 4 + wave;
  int t = tbi[bl], s = bsi[bl];
  const float* tr = tok + (long)t * cD;
  const float* sr = seg + (long)s * cD;
  float x[12];
  float ls = 0.f;
#pragma unroll
  for (int c = 0; c < 12; c++) {
    int d = lane + (c << 6);
    x[c] = tr[d] + sr[d];
    ls += x[c];
  }
  if ((bl & 255) == 0) {
#pragma unroll
    for (int c = 0; c < 12; c++) x64[(bl >> 8) * cD + lane + (c << 6)] = x[c];
  }
  float mean = wsum_all(ls) * (1.f / 768.f);
  float lv = 0.f;
#pragma unroll
  for (int c = 0; c < 12; c++) { float d2 = x[c] - mean; lv += d2 * d2; }
  float var = wsum_all(lv) * (1.f / 767.f);
  float inv = 1.f / (sqrtf(var) + 1e-6f);
  float rdot = 0.f;
#pragma unroll
  for (int c = 0; c < 12; c++) {
    int d = lane + (c << 6);
    float v = ln_a[d] * (x[c] - mean) * inv + ln_b[d];
    gib[bl * cD + d] = __float2bfloat16(v);
    rdot += v * root_w[d];
  }
  float tot = wsum_all(rdot);
  if (lane == 0) e1[bl] = tot;
}

// ---------------- pooled GEMV partials ----------------
__global__ __launch_bounds__(256) void k_pool1(
    const float* __restrict__ x64, const float* __restrict__ pw,
    float* __restrict__ pacc) {
  __shared__ float pws[48][256];
  __shared__ float xs[16][48];
  int i0 = blockIdx.x * 48, j0 = blockIdx.y * 256, b0 = blockIdx.z * 16;
  for (int r = 0; r < 48; r++) pws[r][threadIdx.x] = pw[(long)(i0 + r) * cD + j0 + threadIdx.x];
  for (int idx = threadIdx.x; idx < 16 * 48; idx += 256)
    xs[idx / 48][idx % 48] = x64[(long)(b0 + idx / 48) * cD + i0 + idx % 48];
  __syncthreads();
  int j = threadIdx.x;
  for (int b = 0; b < 16; b++) {
    float acc = 0.f;
#pragma unroll 8
    for (int i = 0; i < 48; i++) acc += xs[b][i] * pws[i][j];
    atomicAdd(&pacc[(long)(b0 + b) * cD + j0 + j], acc);
  }
}
__global__ __launch_bounds__(256) void k_pool2(
    const float* __restrict__ pacc, const float* __restrict__ pb,
    float* __restrict__ pooled) {
  int b = blockIdx.x;
#pragma unroll
  for (int c = 0; c < 3; c++) {
    int j = (c << 8) + threadIdx.x;
    pooled[(long)b * cD + j] = tanhf(pacc[(long)b * cD + j] + pb[j]);
  }
}

// ---------------- dep LUT ----------------
__global__ __launch_bounds__(256) void k_s45(
    const float* __restrict__ dep_emb, const float* __restrict__ fc1w,
    const float* __restrict__ fc1b, const float* __restrict__ fc2w,
    const float* __restrict__ fc2b, float* __restrict__ s45) {
  int t = blockIdx.x;
  __shared__ float e[300];
  for (int i = threadIdx.x; i < 300; i += 256) e[i] = dep_emb[t * 300 + i];
  __syncthreads();
  int j = threadIdx.x;
  float h = fc1b[j];
  for (int i = 0; i < 300; i++) h += e[i] * fc1w[i * 256 + j];
  h = fmaxf(h, 0.f);
  float tot = blockSum(h * fc2w[j]);
  if (threadIdx.x == 0) s45[t] = tot + fc2b[0];
}

__global__ __launch_bounds__(256) void k_depfeat(
    const int* __restrict__ ori, const float* __restrict__ src_mask,
    const float* __restrict__ s45, float* __restrict__ dep_feat) {
  int b = blockIdx.x, l = threadIdx.x;
  float smv = (l == 0) ? 1.f : src_mask[b * cL + l];
  float sc = s45[ori[b * cL + l]] * smv + (1.f - smv) * (-1e30f);
  float mx = blockMax(sc);
  float ex = expf(sc - mx);
  float sum = blockSum(ex);
  dep_feat[b * cL + l] = ex / sum;
}

// ---------------- bias concat for fused projection ----------------
__global__ void k_bcat(const float* __restrict__ a, const float* __restrict__ b,
                       const float* __restrict__ c, const float* __restrict__ d,
                       float* __restrict__ o) {
  int i = blockIdx.x * 256 + threadIdx.x;
  float v = (i < 768) ? a[i] : (i < 1536) ? b[i - 768] : (i < 2304) ? c[i - 1536] : d[i - 2304];
  o[i] = v;
}

// ---------------- wave-per-row dot ----------------
__global__ __launch_bounds__(256) void k_rowdot(
    const float* __restrict__ X, const float* __restrict__ w, long wstride,
    float* __restrict__ e) {
  int r = blockIdx.x * 4 + (threadIdx.x >> 6);
  int lane = threadIdx.x & 63;
  const float4* row = (const float4*)(X + (long)r * cD);
  const float4* wp = (const float4*)(w + (long)(r >> 8) * wstride);
  float s = 0.f;
#pragma unroll
  for (int c = 0; c < 3; c++) {
    int idx = c * 64 + lane;
    float4 a = row[idx], b = wp[idx];
    s += a.x * b.x + a.y * b.y + a.z * b.z + a.w * b.w;
  }
  s = wsum(s);
  if (lane == 0) e[r] = s;
}

// ---------------- root loss ----------------
__global__ __launch_bounds__(256) void k_root2(
    const float* __restrict__ e1, const float* __restrict__ src_mask,
    const float* __restrict__ aspect_mask, float* __restrict__ out_loss) {
  int b = blockIdx.x, l = threadIdx.x;
  float r = e1[b * cL + l];
  float smv = (l == 0) ? 1.f : src_mask[b * cL + l];
  float sc = r * smv + (1.f - smv) * (-1e30f);
  float mx = blockMax(sc);
  float ex = expf(sc - mx);
  float sum = blockSum(ex);
  float p = ex / sum;
  float tot = blockSum(p * aspect_mask[b * cL + l]);
  if (l == 0) atomicAdd(out_loss, -logf(tot + 1e-9f) * (1.f / 64.f));
}

// ---------------- lexicon loss ----------------
__global__ __launch_bounds__(256) void k_lex2(
    const float* __restrict__ e2, const float* __restrict__ src_mask,
    const float* __restrict__ lex, float* __restrict__ out_loss) {
  int b = blockIdx.x, l = threadIdx.x;
  float e = e2[b * cL + l];
  float mx = blockMax(e);
  float ex = expf(e - mx);
  float sum = blockSum(ex);
  float mult = (l == 0) ? 0.f : src_mask[b * cL + l];
  float lw = ex / sum * 50.f * mult;
  float d2 = lw - lex[b * cL + l];
  float tot = blockSum(d2 * d2);
  if (l == 0) atomicAdd(out_loss, tot * (1.f / (64.f * 256.f)));
}

// ---------------- hlsum partials ----------------
__global__ __launch_bounds__(256) void k_hl(
    const float* __restrict__ H, const float* __restrict__ src_mask,
    float* __restrict__ hlsum) {
  int b = blockIdx.z, d = (blockIdx.y << 8) + threadIdx.x, l0 = blockIdx.x * 32;
  float acc = 0.f;
  for (int l = l0; l < l0 + 32; l++) {
    float smv = (l == 0) ? 1.f : src_mask[b * cL + l];
    acc += H[((long)b * cL + l) * cD + d] * smv;
  }
  atomicAdd(&hlsum[(long)b * cD + d], acc);
}

// ---------------- attn weights + asum ----------------
__global__ __launch_bounds__(256) void k_attnw(
    const float* __restrict__ sraw, const float* __restrict__ src_mask,
    const float* __restrict__ am, float* __restrict__ wgt, float* __restrict__ asum) {
  int b = blockIdx.x, k = threadIdx.x;
  float smk = (k == 0) ? 1.f : src_mask[b * cL + k];
  float s = sraw[b * cL + k] * smk * 0.001f;
  float mx = blockMax(s);
  float ex = expf(s - mx);
  float sum = blockSum(ex);
  wgt[b * cL + k] = ex / sum;
  float a = blockSum(am[b * cL + k]);
  if (k == 0) asum[b] = a;
}

// ---------------- fused outputs+sempool partials ----------------
__global__ __launch_bounds__(256) void k_wsum(
    const float* __restrict__ Isem, const float* __restrict__ wgt,
    const float* __restrict__ am, float* __restrict__ outputs,
    float* __restrict__ sempool) {
  int b = blockIdx.z, d = (blockIdx.y << 8) + threadIdx.x, l0 = blockIdx.x * 32;
  float accO = 0.f, accS = 0.f;
  for (int l = l0; l < l0 + 32; l++) {
    float v = Isem[((long)b * cL + l) * cD + d];
    accO += wgt[b * cL + l] * v;
    accS += am[b * cL + l] * v;
  }
  atomicAdd(&outputs[(long)b * cD + d], accO);
  atomicAdd(&sempool[(long)b * cD + d], accS);
}

// ---------------- logits ----------------
__global__ __launch_bounds__(256) void k_logits(
    const float* __restrict__ outputs, const float* __restrict__ sempool,
    const float* __restrict__ pooled, const float* __restrict__ asum,
    const float* __restrict__ cw, const float* __restrict__ cb,
    float* __restrict__ out) {
  int b = blockIdx.x;
  float inv = 1.f / (asum[b] + 1e-9f);
  float a0 = 0.f, a1 = 0.f, a2 = 0.f;
  for (int i = threadIdx.x; i < 3 * cD; i += 256) {
    float f = (i < cD) ? outputs[(long)b * cD + i]
              : (i < 2 * cD) ? sempool[(long)b * cD + i - cD] * inv
                             : pooled[(long)b * cD + i - 2 * cD];
    a0 += f * cw[i * 3 + 0];
    a1 += f * cw[i * 3 + 1];
    a2 += f * cw[i * 3 + 2];
  }
  a0 = blockSum(a0);
  a1 = blockSum(a1);
  a2 = blockSum(a2);
  if (threadIdx.x == 0) {
    out[b * 3 + 0] = a0 + cb[0];
    out[b * 3 + 1] = a1 + cb[1];
    out[b * 3 + 2] = a2 + cb[2];
  }
}

extern "C" void kernel_launch(void* const* d_in, const int* in_sizes, int n_in,
                              void* d_out, int out_size, void* d_ws, size_t ws_size,
                              hipStream_t stream) {
  const int* tbi = (const int*)d_in[0];
  const int* bsi = (const int*)d_in[1];
  const float* src_mask = (const float*)d_in[3];
  const float* aspect_mask = (const float*)d_in[4];
  const float* lex = (const float*)d_in[5];
  const int* ori = (const int*)d_in[6];
  const int* head = (const int*)d_in[7];
  const float* tok_emb = (const float*)d_in[8];
  const float* seg_emb = (const float*)d_in[9];
  const float* pool_w = (const float*)d_in[10];
  const float* pool_b = (const float*)d_in[11];
  const float* ln_a = (const float*)d_in[12];
  const float* ln_b = (const float*)d_in[13];
  const float* dep_emb = (const float*)d_in[14];
  const float* fc1_w = (const float*)d_in[15];
  const float* fc1_b = (const float*)d_in[16];
  const float* fc2_w = (const float*)d_in[17];
  const float* fc2_b = (const float*)d_in[18];
  const float* aq_w = (const float*)d_in[19];
  const float* aq_b = (const float*)d_in[20];
  const float* ak_w = (const float*)d_in[21];
  const float* ak_b = (const float*)d_in[22];
  const float* lq_w = (const float*)d_in[23];
  const float* lq_b = (const float*)d_in[24];
  const float* lk_w = (const float*)d_in[25];
  const float* lk_b = (const float*)d_in[26];
  const float* root_w = (const float*)d_in[27];
  const float* gcn_w = (const float*)d_in[28];
  const float* gcn_b = (const float*)d_in[29];
  const float* fc3_w = (const float*)d_in[30];
  const float* fc3_b = (const float*)d_in[31];
  const float* cls_w = (const float*)d_in[32];
  const float* cls_b = (const float*)d_in[33];
  const float* vlin_w = (const float*)d_in[34];

  float* out = (float*)d_out;
  float* ws = (float*)d_ws;
  // fp32 region
  float* gcnH = ws;            // BLD (H2 f32, written by layer-1 fc3)
  float* Isem = gcnH + BLD;    // BLD
  float* depfeat = Isem + BLD;         // B*L
  float* s45 = depfeat + cB * cL;      // 64
  float* pooled = s45 + 64;            // B*D
  float* x64 = pooled + cB * cD;       // B*D
  float* hlsum = x64 + cB * cD;        // B*D  --- zeroed region start
  float* outputs = hlsum + cB * cD;    // B*D
  float* sempool = outputs + cB * cD;  // B*D
  float* pacc = sempool + cB * cD;     // B*D  --- zeroed region end
  float* e1 = pacc + cB * cD;          // B*L
  float* e2 = e1 + cB * cL;            // B*L
  float* sraw = e2 + cB * cL;          // B*L
  float* wgt = sraw + cB * cL;         // B*L
  float* asum = wgt + cB * cL;         // 64
  float* catb = asum + 64;             // 3072
  // bf16 region
  __hip_bfloat16* gib = (__hip_bfloat16*)(catb + 3072);  // BLD (H state, bf16)
  __hip_bfloat16* qkb = gib + BLD;             // 4*BLD (q|k|q2|k2, ldc=3072)
  __hip_bfloat16* scores = qkb + 4 * BLD;      // (unused, kept for layout)
  __hip_bfloat16* adjag_b = scores + 8 * BLL;  // BLL
  __hip_bfloat16* adjlat_b = adjag_b + BLL;    // BLL
  __hip_bfloat16* wbt = adjlat_b + BLL;        // 7*D*D
  // aliases
  __hip_bfloat16* HWbT = qkb + BLD;     // BLD (HW^T, written directly by EPI=4)
  __hip_bfloat16* Icb = qkb + 2 * BLD;  // BLD

  hipMemsetAsync((char*)d_out + 192 * sizeof(float), 0, 2 * sizeof(float), stream);
  hipMemsetAsync(hlsum, 0, 4 * cB * cD * sizeof(float), stream);

  // ---- prologue ----
  k_gcnin<<<cB * cL / 4, 256, 0, stream>>>(tbi, bsi, tok_emb, seg_emb, ln_a, ln_b,
                                           root_w, gib, x64, e1);
  k_s45<<<45, 256, 0, stream>>>(dep_emb, fc1_w, fc1_b, fc2_w, fc2_b, s45);
  k_depfeat<<<cB, 256, 0, stream>>>(ori, src_mask, s45, depfeat);
  k_pool1<<<dim3(16, 3, 4), 256, 0, stream>>>(x64, pool_w, pacc);
  k_pool2<<<cB, 256, 0, stream>>>(pacc, pool_b, pooled);
  k_bcat<<<12, 256, 0, stream>>>(aq_b, ak_b, lq_b, lk_b, catb);
  k_wconv7<<<dim3(24, 24, 7), dim3(32, 8), 0, stream>>>(
      aq_w, ak_w, lq_w, lk_w, gcn_w, gcn_w + (long)cD * cD, fc3_w, wbt);

  const long DD = (long)cD * cD;
  const long LD = cLD;

  // ---- fused 4-way projection: qkb = gib @ [aq|ak|lq|lk] + catb ----
  bgemm<1, 0, 1, 0><<<dim3(24, 128, 1), 256, 0, stream>>>(
      gib, wbt, qkb, catb, nullptr, nullptr, cD, cD, cD, 3072,
      0, 0, 0, 0, 0, 0, 0, 0);

  // ---- fused adjacency builders (replace scores/latsc GEMMs + softmax passes) ----
  k_qkadj<8><<<dim3(4, cB), 256, 0, stream>>>(qkb, src_mask, nullptr, nullptr, adjag_b);
  k_qkadj<1><<<dim3(4, cB), 256, 0, stream>>>(qkb, src_mask, head, depfeat, adjlat_b);

  // ---- root loss (e1 fused into k_gcnin) ----
  k_root2<<<cB, 256, 0, stream>>>(e1, src_mask, aspect_mask, out + 192);

  // ---- GCN loop ----
  for (int layer = 0; layer < 2; layer++) {
    const float* bb = gcn_b + (long)layer * cD;
    // HW^T = (H @ W)^T written directly (EPI=4), layout (b, d, l)
    bgemm<1, 0, 0, 4><<<dim3(6, 128, 1), 256, 0, stream>>>(
        gib, wbt + (4 + layer) * DD, HWbT, nullptr, nullptr, nullptr,
        cD, cD, cD, cD, 0, 0, 0, 0, 0, 0, LD, 0);
    // dual adjacency GEMM + fused I_com epilogue (writes Isem f32 on last layer)
    bgemm_dual<<<dim3(6, 2, cB), 256, 0, stream>>>(
        adjag_b, adjlat_b, HWbT, Isem, Icb, bb, layer == 1 ? 1 : 0);
    // fc3 GEMM + H-gate epilogue on bf16 H (gib); f32 H only on last layer (tail)
    bgemm<0, 1, 1, 2><<<dim3(6, 128, 1), 256, 0, stream>>>(
        Icb, wbt + 6 * DD, nullptr, fc3_b, layer == 1 ? gcnH : nullptr, gib,
        cD, cD, cD, cD, 0, 0, 0, 0, 0, 0, 0, 0);
  }

  // ---- tail ----
  k_hl<<<dim3(8, 3, cB), 256, 0, stream>>>(gcnH, src_mask, hlsum);
  k_rowdot<<<cB * cL / 4, 256, 0, stream>>>(Isem, hlsum, cD, sraw);
  k_attnw<<<cB, 256, 0, stream>>>(sraw, src_mask, aspect_mask, wgt, asum);
  k_wsum<<<dim3(8, 3, cB), 256, 0, stream>>>(Isem, wgt, aspect_mask, outputs, sempool);
  k_logits<<<cB, 256, 0, stream>>>(outputs, sempool, pooled, asum, cls_w, cls_b, out);
  k_rowdot<<<cB * cL / 4, 256, 0, stream>>>(gcnH, vlin_w, 0, e2);
  k_lex2<<<cB, 256, 0, stream>>>(e2, src_mask, lex, out + 193);
}

// Round 5
// 802.262 us; speedup vs baseline: 1.1301x; 1.0060x over previous
//
#include <hip/hip_runtime.h>
#include <hip/hip_bf16.h>
#include <math.h>

#define DI __device__ __forceinline__

constexpr int cB = 64, cL = 256, cD = 768;
constexpr long BLD = (long)cB * cL * cD;   // 12,582,912
constexpr long BLL = (long)cB * cL * cL;   //  4,194,304
constexpr long cLL = (long)cL * cL;
constexpr long cLD = (long)cL * cD;

typedef __attribute__((ext_vector_type(8))) short b8;
typedef __attribute__((ext_vector_type(4))) float f4;

// async global->LDS, 16B per lane, dest = wave-uniform base + lane*16 (linear)
#define GLDS(g, l)                                                    \
  __builtin_amdgcn_global_load_lds(                                   \
      (const __attribute__((address_space(1))) void*)(g),             \
      (__attribute__((address_space(3))) void*)(l), 16, 0, 0)

// ---------------- reductions (wave64) ----------------
DI float wsum(float v) {
#pragma unroll
  for (int o = 32; o > 0; o >>= 1) v += __shfl_down(v, o, 64);
  return v;
}
DI float wsum_all(float v) {
#pragma unroll
  for (int m = 32; m > 0; m >>= 1) v += __shfl_xor(v, m, 64);
  return v;
}
DI float wmaxr(float v) {
#pragma unroll
  for (int o = 32; o > 0; o >>= 1) v = fmaxf(v, __shfl_down(v, o, 64));
  return v;
}
DI float blockSum(float v) {
  __shared__ float sh[4];
  v = wsum(v);
  __syncthreads();
  if ((threadIdx.x & 63) == 0) sh[threadIdx.x >> 6] = v;
  __syncthreads();
  return sh[0] + sh[1] + sh[2] + sh[3];
}
DI float blockMax(float v) {
  __shared__ float sh[4];
  v = wmaxr(v);
  __syncthreads();
  if ((threadIdx.x & 63) == 0) sh[threadIdx.x >> 6] = v;
  __syncthreads();
  return fmaxf(fmaxf(sh[0], sh[1]), fmaxf(sh[2], sh[3]));
}
DI float sigf(float x) { return 1.f / (1.f + expf(-x)); }

// ================= bf16 MFMA GEMM: C = A(MxK) @ BT(NxK)^T =================
// 128x128 tile, 4 waves, 4x4 of 16x16x32 frags/wave, BK=32.
// Staging via global_load_lds width=16; linear LDS [128][32] per tile.
// SWZ: XCD-contiguous tile remap (T1) — requires gridDim.x*gridDim.y % 8 == 0.
// EPI: 0=plain (OBF/RELU), 2=H-update (gate vs bf16 H in auxb; optional f32 out),
//      4=transposed bf16 write (per-256-row batch).
template <int OBF, int RELU, int BIAS, int EPI, int SWZ>
__global__ __launch_bounds__(256, 2) void bgemm(
    const __hip_bfloat16* __restrict__ A, const __hip_bfloat16* __restrict__ BT,
    void* __restrict__ Cv, const float* __restrict__ bias,
    float* __restrict__ auxf, __hip_bfloat16* __restrict__ auxb,
    int K, int lda, int ldb, int ldc,
    int zshift, int zmask, long sA1, long sA2, long sB1, long sB2, long sC,
    int czdiv) {
  __shared__ __hip_bfloat16 Asp[128 * 32];
  __shared__ __hip_bfloat16 Bsp[128 * 32];
  int bx = blockIdx.x, by = blockIdx.y;
  if (SWZ) {
    int gx = gridDim.x;
    int nb = gx * gridDim.y;
    int id = by * gx + bx;
    int cpx = nb >> 3;
    id = (id & 7) * cpx + (id >> 3);  // XCD k executes contiguous chunk k
    bx = id % gx;
    by = id / gx;
  }
  int z = blockIdx.z;
  A += (long)(z >> zshift) * sA1 + (long)(z & zmask) * sA2;
  BT += (long)(z >> zshift) * sB1 + (long)(z & zmask) * sB2;
  int tid = threadIdx.x;
  int lane = tid & 63, w = tid >> 6;
  int wr = w >> 1, wc = w & 1;
  int l16 = lane & 15, q = lane >> 4;
  int m0 = by << 7, n0 = bx << 7;

  int fm = tid >> 2, fq = tid & 3;
  const __hip_bfloat16* Ap0 = A + (long)(m0 + fm) * lda + fq * 8;
  const __hip_bfloat16* Ap1 = A + (long)(m0 + fm + 64) * lda + fq * 8;
  const __hip_bfloat16* Bp0 = BT + (long)(n0 + fm) * ldb + fq * 8;
  const __hip_bfloat16* Bp1 = BT + (long)(n0 + fm + 64) * ldb + fq * 8;
  char* Aw0 = (char*)Asp + (w << 10);
  char* Aw1 = (char*)Asp + 4096 + (w << 10);
  char* Bw0 = (char*)Bsp + (w << 10);
  char* Bw1 = (char*)Bsp + 4096 + (w << 10);

  f4 acc[4][4];
#pragma unroll
  for (int i = 0; i < 4; i++)
#pragma unroll
    for (int j = 0; j < 4; j++) acc[i][j] = (f4){0.f, 0.f, 0.f, 0.f};

  for (int k0 = 0; k0 < K; k0 += 32) {
    GLDS(Ap0 + k0, Aw0);
    GLDS(Ap1 + k0, Aw1);
    GLDS(Bp0 + k0, Bw0);
    GLDS(Bp1 + k0, Bw1);
    __syncthreads();
    b8 af[4], bf[4];
#pragma unroll
    for (int i = 0; i < 4; i++)
      af[i] = *(const b8*)&Asp[(wr * 64 + i * 16 + l16) * 32 + q * 8];
#pragma unroll
    for (int j = 0; j < 4; j++)
      bf[j] = *(const b8*)&Bsp[(wc * 64 + j * 16 + l16) * 32 + q * 8];
#pragma unroll
    for (int i = 0; i < 4; i++)
#pragma unroll
      for (int j = 0; j < 4; j++)
        acc[i][j] = __builtin_amdgcn_mfma_f32_16x16x32_bf16(af[i], bf[j], acc[i][j], 0, 0, 0);
    __syncthreads();
  }
  if (EPI == 4) {
#pragma unroll
    for (int j = 0; j < 4; j++) {
      int n = n0 + wc * 64 + j * 16 + l16;
#pragma unroll
      for (int i = 0; i < 4; i++) {
        int m = m0 + wr * 64 + i * 16 + (q << 2);
        __hip_bfloat16 t4[4];
#pragma unroll
        for (int r = 0; r < 4; r++) t4[r] = __float2bfloat16(acc[i][j][r]);
        long bidx = (long)(m >> 8) * sC + (long)n * cL + (m & 255);
        *(uint2*)&((__hip_bfloat16*)Cv)[bidx] = *(uint2*)t4;
      }
    }
    return;
  }
  long cz = (long)(z >> czdiv) * sC;
#pragma unroll
  for (int j = 0; j < 4; j++) {
    int n = n0 + wc * 64 + j * 16 + l16;
    float bv = BIAS ? bias[n] : 0.f;
#pragma unroll
    for (int i = 0; i < 4; i++) {
#pragma unroll
      for (int r = 0; r < 4; r++) {
        int m = m0 + wr * 64 + i * 16 + q * 4 + r;
        long idx = cz + (long)m * ldc + n;
        float v = acc[i][j][r] + bv;
        if (EPI == 0) {
          if (RELU) v = fmaxf(v, 0.f);
          if (OBF)
            ((__hip_bfloat16*)Cv)[idx] = __float2bfloat16(v);
          else
            ((float*)Cv)[idx] = v;
        } else {
          // EPI==2: v = Hout = relu(acc+bias); h = bf16 H (auxb);
          // H' = h + sig(h)*(Hout - h); write bf16 always, f32 only if auxf.
          v = fmaxf(v, 0.f);
          float h = __bfloat162float(auxb[idx]);
          float g = sigf(h);
          float o = h + g * (v - h);
          auxb[idx] = __float2bfloat16(o);
          if (auxf) auxf[idx] = o;
        }
      }
    }
  }
}

// ======== dual adjacency GEMM: Isem/Ilat share BT; fused I_com epilogue ========
// XCD swizzle over full 3D id (768 blocks): each XCD owns 8 consecutive batches.
__global__ __launch_bounds__(256, 2) void bgemm_dual(
    const __hip_bfloat16* __restrict__ A1g, const __hip_bfloat16* __restrict__ A2g,
    const __hip_bfloat16* __restrict__ BTg, float* __restrict__ IsemF,
    __hip_bfloat16* __restrict__ Icb, const float* __restrict__ bias,
    int write_isem) {
  __shared__ __hip_bfloat16 A1sp[128 * 32];
  __shared__ __hip_bfloat16 A2sp[128 * 32];
  __shared__ __hip_bfloat16 Bsp[128 * 32];
  int id = (blockIdx.z * 2 + blockIdx.y) * 6 + blockIdx.x;  // 768 total
  id = (id & 7) * 96 + (id >> 3);
  int bx = id % 6, t = id / 6;
  int by = t & 1, z = t >> 1;
  const __hip_bfloat16* A1 = A1g + (long)z * cLL;
  const __hip_bfloat16* A2 = A2g + (long)z * cLL;
  const __hip_bfloat16* BT = BTg + (long)z * cLD;
  int tid = threadIdx.x;
  int lane = tid & 63, w = tid >> 6;
  int wr = w >> 1, wc = w & 1;
  int l16 = lane & 15, q = lane >> 4;
  int m0 = by << 7, n0 = bx << 7;

  int fm = tid >> 2, fq = tid & 3;
  const __hip_bfloat16* A1p0 = A1 + (long)(m0 + fm) * cL + fq * 8;
  const __hip_bfloat16* A1p1 = A1p0 + 64L * cL;
  const __hip_bfloat16* A2p0 = A2 + (long)(m0 + fm) * cL + fq * 8;
  const __hip_bfloat16* A2p1 = A2p0 + 64L * cL;
  const __hip_bfloat16* Bp0 = BT + (long)(n0 + fm) * cL + fq * 8;
  const __hip_bfloat16* Bp1 = Bp0 + 64L * cL;
  char* w10 = (char*)A1sp + (w << 10);
  char* w11 = (char*)A1sp + 4096 + (w << 10);
  char* w20 = (char*)A2sp + (w << 10);
  char* w21 = (char*)A2sp + 4096 + (w << 10);
  char* wb0 = (char*)Bsp + (w << 10);
  char* wb1 = (char*)Bsp + 4096 + (w << 10);

  f4 ac1[4][4], ac2[4][4];
#pragma unroll
  for (int i = 0; i < 4; i++)
#pragma unroll
    for (int j = 0; j < 4; j++) {
      ac1[i][j] = (f4){0.f, 0.f, 0.f, 0.f};
      ac2[i][j] = (f4){0.f, 0.f, 0.f, 0.f};
    }

  for (int k0 = 0; k0 < cL; k0 += 32) {
    GLDS(A1p0 + k0, w10);
    GLDS(A1p1 + k0, w11);
    GLDS(A2p0 + k0, w20);
    GLDS(A2p1 + k0, w21);
    GLDS(Bp0 + k0, wb0);
    GLDS(Bp1 + k0, wb1);
    __syncthreads();
    b8 a1f[4], a2f[4], bf[4];
#pragma unroll
    for (int i = 0; i < 4; i++) {
      a1f[i] = *(const b8*)&A1sp[(wr * 64 + i * 16 + l16) * 32 + q * 8];
      a2f[i] = *(const b8*)&A2sp[(wr * 64 + i * 16 + l16) * 32 + q * 8];
    }
#pragma unroll
    for (int j = 0; j < 4; j++)
      bf[j] = *(const b8*)&Bsp[(wc * 64 + j * 16 + l16) * 32 + q * 8];
#pragma unroll
    for (int i = 0; i < 4; i++)
#pragma unroll
      for (int j = 0; j < 4; j++) {
        ac1[i][j] = __builtin_amdgcn_mfma_f32_16x16x32_bf16(a1f[i], bf[j], ac1[i][j], 0, 0, 0);
        ac2[i][j] = __builtin_amdgcn_mfma_f32_16x16x32_bf16(a2f[i], bf[j], ac2[i][j], 0, 0, 0);
      }
    __syncthreads();
  }
  long cz = (long)z * cLD;
#pragma unroll
  for (int j = 0; j < 4; j++) {
    int n = n0 + wc * 64 + j * 16 + l16;
    float bv = bias[n];
#pragma unroll
    for (int i = 0; i < 4; i++) {
#pragma unroll
      for (int r = 0; r < 4; r++) {
        int m = m0 + wr * 64 + i * 16 + q * 4 + r;
        long idx = cz + (long)m * cD + n;
        float is = ac1[i][j][r] + bv;
        float il = ac2[i][j][r] + bv;
        float g = 0.5f * sigf(il);
        Icb[idx] = __float2bfloat16(is + g * (il - is));
        if (write_isem) IsemF[idx] = is;
      }
    }
  }
}

// ============ fused QK^T + mask(+dep) + row-softmax -> adjacency (bf16) ============
// blockIdx.z==0: adj_ag (8 heads, qkb cols [0|768)); z==1: adj_lat (cols [1536|2304)).
// Merged into ONE dispatch so both halves co-fill the GPU (each alone = 256 blocks).
__global__ __launch_bounds__(256, 2) void k_qkadj2(
    const __hip_bfloat16* __restrict__ qkb, const float* __restrict__ src_mask,
    const int* __restrict__ headv, const float* __restrict__ df,
    __hip_bfloat16* __restrict__ outAag, __hip_bfloat16* __restrict__ outAlat) {
  const bool lat = blockIdx.z != 0;
  const int NH = lat ? 1 : 8;
  const int KH = lat ? 768 : 96;
  const int QOFF = lat ? 1536 : 0;
  const int KOFF = lat ? 2304 : 768;
  const float scale = lat ? (1.f / sqrtf(768.f)) : (1.f / (sqrtf(96.f) + 1e-9f));
  __shared__ __hip_bfloat16 Qs[64 * 32];   // 4 KB
  __shared__ __hip_bfloat16 Ks[256 * 32];  // 16 KB
  __shared__ float red[4][64];
  const int b = blockIdx.y, m0 = blockIdx.x << 6;
  const int tid = threadIdx.x, lane = tid & 63, w = tid >> 6;
  const int l16 = lane & 15, q = lane >> 4;
  const long rowbase = (long)b * cL;
  const __hip_bfloat16* Qg = qkb + (rowbase + m0 + (tid >> 2)) * 3072 + (tid & 3) * 8 + QOFF;
  const __hip_bfloat16* Kg = qkb + (rowbase + (tid >> 2)) * 3072 + (tid & 3) * 8 + KOFF;
  char* qdst = (char*)Qs + (w << 10);

  float smj[4];
  int hcol[4];
  float dfc[4];
#pragma unroll
  for (int j = 0; j < 4; j++) {
    int col = w * 64 + j * 16 + l16;
    smj[j] = (col == 0) ? 1.f : src_mask[b * cL + col];
    if (lat) {
      hcol[j] = (col >= 1) ? headv[b * cL + col - 1] : -1;
      dfc[j] = (col >= 1) ? df[b * cL + col - 1] : 0.f;
    }
  }
  float smi_[4][4];
  int hrow_[4][4];
  float dfr_[4][4];
#pragma unroll
  for (int i = 0; i < 4; i++)
#pragma unroll
    for (int r = 0; r < 4; r++) {
      int grow = m0 + i * 16 + q * 4 + r;
      smi_[i][r] = (grow == 0) ? 1.f : src_mask[b * cL + grow];
      if (lat) {
        hrow_[i][r] = (grow >= 1) ? headv[b * cL + grow - 1] : -1;
        dfr_[i][r] = (grow >= 1) ? df[b * cL + grow - 1] : 0.f;
      }
    }

  f4 aag[4][4];
#pragma unroll
  for (int i = 0; i < 4; i++)
#pragma unroll
    for (int j = 0; j < 4; j++) aag[i][j] = (f4){0.f, 0.f, 0.f, 0.f};

  f4 sa[4][4];
  float inv_[4][4];
  for (int h = 0; h < NH; h++) {
    const int hk = h * 96;
#pragma unroll
    for (int i = 0; i < 4; i++)
#pragma unroll
      for (int j = 0; j < 4; j++) sa[i][j] = (f4){0.f, 0.f, 0.f, 0.f};
    for (int k0 = 0; k0 < KH; k0 += 32) {
      __syncthreads();  // previous readers of Qs/Ks (and red) done
      GLDS(Qg + hk + k0, qdst);
#pragma unroll
      for (int u = 0; u < 4; u++)
        GLDS(Kg + (long)u * 196608 + hk + k0, (char*)Ks + u * 4096 + (w << 10));
      __syncthreads();  // staged data visible (drains vmcnt)
      b8 af[4], bf[4];
#pragma unroll
      for (int i = 0; i < 4; i++)
        af[i] = *(const b8*)&Qs[(i * 16 + l16) * 32 + q * 8];
#pragma unroll
      for (int j = 0; j < 4; j++)
        bf[j] = *(const b8*)&Ks[(w * 64 + j * 16 + l16) * 32 + q * 8];
#pragma unroll
      for (int i = 0; i < 4; i++)
#pragma unroll
        for (int j = 0; j < 4; j++)
          sa[i][j] = __builtin_amdgcn_mfma_f32_16x16x32_bf16(af[i], bf[j], sa[i][j], 0, 0, 0);
    }
    // mask/scale (+dep for latent)
#pragma unroll
    for (int i = 0; i < 4; i++)
#pragma unroll
      for (int j = 0; j < 4; j++)
#pragma unroll
        for (int r = 0; r < 4; r++) {
          float raw = sa[i][j][r];
          float v;
          if (lat) {
            int grow = m0 + i * 16 + q * 4 + r;
            int col = w * 64 + j * 16 + l16;
            float dep = 1.f;
            if (hcol[j] == grow) dep = dfc[j];
            if (col == hrow_[i][r]) dep = dfr_[i][r];
            v = raw * scale + dep + (1.f - smj[j]) * -10000.f;
          } else {
            v = (smj[j] == 0.f) ? -1e9f : raw * scale;
          }
          sa[i][j][r] = v;
        }
    // row max
    float rm_[4][4];
#pragma unroll
    for (int i = 0; i < 4; i++)
#pragma unroll
      for (int r = 0; r < 4; r++) {
        float m = fmaxf(fmaxf(sa[i][0][r], sa[i][1][r]), fmaxf(sa[i][2][r], sa[i][3][r]));
#pragma unroll
        for (int o = 1; o < 16; o <<= 1) m = fmaxf(m, __shfl_xor(m, o, 64));
        if (l16 == 0) red[w][i * 16 + q * 4 + r] = m;
        rm_[i][r] = m;
      }
    __syncthreads();
#pragma unroll
    for (int i = 0; i < 4; i++)
#pragma unroll
      for (int r = 0; r < 4; r++) {
        int lr = i * 16 + q * 4 + r;
        rm_[i][r] = fmaxf(fmaxf(red[0][lr], red[1][lr]), fmaxf(red[2][lr], red[3][lr]));
      }
    __syncthreads();
    // exp + row sum
#pragma unroll
    for (int i = 0; i < 4; i++)
#pragma unroll
      for (int r = 0; r < 4; r++) {
        float s0 = 0.f;
#pragma unroll
        for (int j = 0; j < 4; j++) {
          float e = expf(sa[i][j][r] - rm_[i][r]);
          sa[i][j][r] = e;
          s0 += e;
        }
#pragma unroll
        for (int o = 1; o < 16; o <<= 1) s0 += __shfl_xor(s0, o, 64);
        if (l16 == 0) red[w][i * 16 + q * 4 + r] = s0;
      }
    __syncthreads();
#pragma unroll
    for (int i = 0; i < 4; i++)
#pragma unroll
      for (int r = 0; r < 4; r++) {
        int lr = i * 16 + q * 4 + r;
        inv_[i][r] = 1.f / (red[0][lr] + red[1][lr] + red[2][lr] + red[3][lr]);
      }
    if (!lat) {
#pragma unroll
      for (int i = 0; i < 4; i++)
#pragma unroll
        for (int j = 0; j < 4; j++)
#pragma unroll
          for (int r = 0; r < 4; r++) aag[i][j][r] += sa[i][j][r] * inv_[i][r];
    }
  }
  __hip_bfloat16* outA = lat ? outAlat : outAag;
#pragma unroll
  for (int j = 0; j < 4; j++) {
    int col = w * 64 + j * 16 + l16;
#pragma unroll
    for (int i = 0; i < 4; i++)
#pragma unroll
      for (int r = 0; r < 4; r++) {
        int grow = m0 + i * 16 + q * 4 + r;
        float p = lat ? sa[i][j][r] * inv_[i][r] : aag[i][j][r] * 0.125f;
        float v = (col == grow) ? 1.f : p;
        outA[((long)b * cL + grow) * cL + col] = __float2bfloat16(v * smi_[i][r]);
      }
  }
}

// -------- 7 weight convert+transpose + bias-concat (z==7) in one dispatch --------
__global__ void k_wconv7(const float* __restrict__ s0, const float* __restrict__ s1,
                         const float* __restrict__ s2, const float* __restrict__ s3,
                         const float* __restrict__ s4, const float* __restrict__ s5,
                         const float* __restrict__ s6, __hip_bfloat16* __restrict__ dst,
                         const float* __restrict__ ba, const float* __restrict__ bb,
                         const float* __restrict__ bc, const float* __restrict__ bd,
                         float* __restrict__ catb) {
  if (blockIdx.z == 7) {
    if (blockIdx.y != 0 || blockIdx.x >= 12) return;
    int tid = threadIdx.y * 32 + threadIdx.x;
    int i = blockIdx.x * 256 + tid;
    float v = (i < 768) ? ba[i] : (i < 1536) ? bb[i - 768]
              : (i < 2304) ? bc[i - 1536] : bd[i - 2304];
    catb[i] = v;
    return;
  }
  const float* srcs[7] = {s0, s1, s2, s3, s4, s5, s6};
  const float* src = srcs[blockIdx.z];
  __hip_bfloat16* d = dst + (long)blockIdx.z * cD * cD;
  __shared__ float t[32][33];
  int k0 = blockIdx.x * 32, n0 = blockIdx.y * 32;
  int tx = threadIdx.x, ty = threadIdx.y;
#pragma unroll
  for (int i = 0; i < 32; i += 8) t[ty + i][tx] = src[(long)(k0 + ty + i) * cD + n0 + tx];
  __syncthreads();
#pragma unroll
  for (int i = 0; i < 32; i += 8)
    d[(long)(n0 + ty + i) * cD + k0 + tx] = __float2bfloat16(t[tx][ty + i]);
}

// -------- embedding + layernorm + root dot, wave-per-row (bf16-only H out) --------
__global__ __launch_bounds__(256) void k_gcnin(
    const int* __restrict__ tbi, const int* __restrict__ bsi,
    const float* __restrict__ tok, const float* __restrict__ seg,
    const float* __restrict__ ln_a, const float* __restrict__ ln_b,
    const float* __restrict__ root_w, __hip_bfloat16* __restrict__ gib,
    float* __restrict__ x64, float* __restrict__ e1) {
  int wave = threadIdx.x >> 6, lane = threadIdx.x & 63;
  long bl = (long)blockIdx.x * 4 + wave;
  int t = tbi[bl], s = bsi[bl];
  const float* tr = tok + (long)t * cD;
  const float* sr = seg + (long)s * cD;
  float x[12];
  float ls = 0.f;
#pragma unroll
  for (int c = 0; c < 12; c++) {
    int d = lane + (c << 6);
    x[c] = tr[d] + sr[d];
    ls += x[c];
  }
  if ((bl & 255) == 0) {
#pragma unroll
    for (int c = 0; c < 12; c++) x64[(bl >> 8) * cD + lane + (c << 6)] = x[c];
  }
  float mean = wsum_all(ls) * (1.f / 768.f);
  float lv = 0.f;
#pragma unroll
  for (int c = 0; c < 12; c++) { float d2 = x[c] - mean; lv += d2 * d2; }
  float var = wsum_all(lv) * (1.f / 767.f);
  float inv = 1.f / (sqrtf(var) + 1e-6f);
  float rdot = 0.f;
#pragma unroll
  for (int c = 0; c < 12; c++) {
    int d = lane + (c << 6);
    float v = ln_a[d] * (x[c] - mean) * inv + ln_b[d];
    gib[bl * cD + d] = __float2bfloat16(v);
    rdot += v * root_w[d];
  }
  float tot = wsum_all(rdot);
  if (lane == 0) e1[bl] = tot;
}

// ---------------- pooled GEMV partials ----------------
__global__ __launch_bounds__(256) void k_pool1(
    const float* __restrict__ x64, const float* __restrict__ pw,
    float* __restrict__ pacc) {
  __shared__ float pws[48][256];
  __shared__ float xs[16][48];
  int i0 = blockIdx.x * 48, j0 = blockIdx.y * 256, b0 = blockIdx.z * 16;
  for (int r = 0; r < 48; r++) pws[r][threadIdx.x] = pw[(long)(i0 + r) * cD + j0 + threadIdx.x];
  for (int idx = threadIdx.x; idx < 16 * 48; idx += 256)
    xs[idx / 48][idx % 48] = x64[(long)(b0 + idx / 48) * cD + i0 + idx % 48];
  __syncthreads();
  int j = threadIdx.x;
  for (int b = 0; b < 16; b++) {
    float acc = 0.f;
#pragma unroll 8
    for (int i = 0; i < 48; i++) acc += xs[b][i] * pws[i][j];
    atomicAdd(&pacc[(long)(b0 + b) * cD + j0 + j], acc);
  }
}

// ---------------- dep LUT ----------------
__global__ __launch_bounds__(256) void k_s45(
    const float* __restrict__ dep_emb, const float* __restrict__ fc1w,
    const float* __restrict__ fc1b, const float* __restrict__ fc2w,
    const float* __restrict__ fc2b, float* __restrict__ s45) {
  int t = blockIdx.x;
  __shared__ float e[300];
  for (int i = threadIdx.x; i < 300; i += 256) e[i] = dep_emb[t * 300 + i];
  __syncthreads();
  int j = threadIdx.x;
  float h = fc1b[j];
  for (int i = 0; i < 300; i++) h += e[i] * fc1w[i * 256 + j];
  h = fmaxf(h, 0.f);
  float tot = blockSum(h * fc2w[j]);
  if (threadIdx.x == 0) s45[t] = tot + fc2b[0];
}

__global__ __launch_bounds__(256) void k_depfeat(
    const int* __restrict__ ori, const float* __restrict__ src_mask,
    const float* __restrict__ s45, float* __restrict__ dep_feat) {
  int b = blockIdx.x, l = threadIdx.x;
  float smv = (l == 0) ? 1.f : src_mask[b * cL + l];
  float sc = s45[ori[b * cL + l]] * smv + (1.f - smv) * (-1e30f);
  float mx = blockMax(sc);
  float ex = expf(sc - mx);
  float sum = blockSum(ex);
  dep_feat[b * cL + l] = ex / sum;
}

// ---------------- merged wave-per-row dots: y==0 sraw=Isem.hlsum, y==1 e2=H.vlin ----------------
__global__ __launch_bounds__(256) void k_rowdot2(
    const float* __restrict__ Isem, const float* __restrict__ hlsum,
    const float* __restrict__ gcnH, const float* __restrict__ vlin,
    float* __restrict__ sraw, float* __restrict__ e2) {
  int r = blockIdx.x * 4 + (threadIdx.x >> 6);
  int lane = threadIdx.x & 63;
  bool z = blockIdx.y != 0;
  const float4* row = (const float4*)((z ? gcnH : Isem) + (long)r * cD);
  const float4* wp = z ? (const float4*)vlin
                       : (const float4*)(hlsum + (long)(r >> 8) * cD);
  float s = 0.f;
#pragma unroll
  for (int c = 0; c < 3; c++) {
    int idx = c * 64 + lane;
    float4 a = row[idx], b = wp[idx];
    s += a.x * b.x + a.y * b.y + a.z * b.z + a.w * b.w;
  }
  s = wsum(s);
  if (lane == 0) (z ? e2 : sraw)[r] = s;
}

// -------- merged per-batch tail reductions: attn weights + root loss + lex loss --------
__global__ __launch_bounds__(256) void k_tailred(
    const float* __restrict__ sraw, const float* __restrict__ e1,
    const float* __restrict__ e2, const float* __restrict__ src_mask,
    const float* __restrict__ aspect_mask, const float* __restrict__ lex,
    float* __restrict__ wgt, float* __restrict__ asum,
    float* __restrict__ out_root, float* __restrict__ out_lex) {
  int b = blockIdx.x, l = threadIdx.x;
  float smv = (l == 0) ? 1.f : src_mask[b * cL + l];
  float am = aspect_mask[b * cL + l];
  // attn weights + asum
  float s = sraw[b * cL + l] * smv * 0.001f;
  float mx = blockMax(s);
  float ex = expf(s - mx);
  float sum = blockSum(ex);
  wgt[b * cL + l] = ex / sum;
  float a = blockSum(am);
  if (l == 0) asum[b] = a;
  // root loss
  float sc = e1[b * cL + l] * smv + (1.f - smv) * (-1e30f);
  float mx2 = blockMax(sc);
  float ex2 = expf(sc - mx2);
  float sum2 = blockSum(ex2);
  float tot = blockSum((ex2 / sum2) * am);
  if (l == 0) atomicAdd(out_root, -logf(tot + 1e-9f) * (1.f / 64.f));
  // lexicon loss
  float e = e2[b * cL + l];
  float mx3 = blockMax(e);
  float ex3 = expf(e - mx3);
  float sum3 = blockSum(ex3);
  float mult = (l == 0) ? 0.f : src_mask[b * cL + l];
  float lw = ex3 / sum3 * 50.f * mult;
  float d2 = lw - lex[b * cL + l];
  float t3 = blockSum(d2 * d2);
  if (l == 0) atomicAdd(out_lex, t3 * (1.f / (64.f * 256.f)));
}

// ---------------- hlsum partials ----------------
__global__ __launch_bounds__(256) void k_hl(
    const float* __restrict__ H, const float* __restrict__ src_mask,
    float* __restrict__ hlsum) {
  int b = blockIdx.z, d = (blockIdx.y << 8) + threadIdx.x, l0 = blockIdx.x * 32;
  float acc = 0.f;
  for (int l = l0; l < l0 + 32; l++) {
    float smv = (l == 0) ? 1.f : src_mask[b * cL + l];
    acc += H[((long)b * cL + l) * cD + d] * smv;
  }
  atomicAdd(&hlsum[(long)b * cD + d], acc);
}

// ---------------- fused outputs+sempool partials ----------------
__global__ __launch_bounds__(256) void k_wsum(
    const float* __restrict__ Isem, const float* __restrict__ wgt,
    const float* __restrict__ am, float* __restrict__ outputs,
    float* __restrict__ sempool) {
  int b = blockIdx.z, d = (blockIdx.y << 8) + threadIdx.x, l0 = blockIdx.x * 32;
  float accO = 0.f, accS = 0.f;
  for (int l = l0; l < l0 + 32; l++) {
    float v = Isem[((long)b * cL + l) * cD + d];
    accO += wgt[b * cL + l] * v;
    accS += am[b * cL + l] * v;
  }
  atomicAdd(&outputs[(long)b * cD + d], accO);
  atomicAdd(&sempool[(long)b * cD + d], accS);
}

// ---------------- logits (pooled = tanh(pacc+pb) folded in) ----------------
__global__ __launch_bounds__(256) void k_logits(
    const float* __restrict__ outputs, const float* __restrict__ sempool,
    const float* __restrict__ pacc, const float* __restrict__ pb,
    const float* __restrict__ asum, const float* __restrict__ cw,
    const float* __restrict__ cb, float* __restrict__ out) {
  int b = blockIdx.x;
  float inv = 1.f / (asum[b] + 1e-9f);
  float a0 = 0.f, a1 = 0.f, a2 = 0.f;
  for (int i = threadIdx.x; i < 3 * cD; i += 256) {
    float f;
    if (i < cD)
      f = outputs[(long)b * cD + i];
    else if (i < 2 * cD)
      f = sempool[(long)b * cD + i - cD] * inv;
    else
      f = tanhf(pacc[(long)b * cD + i - 2 * cD] + pb[i - 2 * cD]);
    a0 += f * cw[i * 3 + 0];
    a1 += f * cw[i * 3 + 1];
    a2 += f * cw[i * 3 + 2];
  }
  a0 = blockSum(a0);
  a1 = blockSum(a1);
  a2 = blockSum(a2);
  if (threadIdx.x == 0) {
    out[b * 3 + 0] = a0 + cb[0];
    out[b * 3 + 1] = a1 + cb[1];
    out[b * 3 + 2] = a2 + cb[2];
  }
}

extern "C" void kernel_launch(void* const* d_in, const int* in_sizes, int n_in,
                              void* d_out, int out_size, void* d_ws, size_t ws_size,
                              hipStream_t stream) {
  const int* tbi = (const int*)d_in[0];
  const int* bsi = (const int*)d_in[1];
  const float* src_mask = (const float*)d_in[3];
  const float* aspect_mask = (const float*)d_in[4];
  const float* lex = (const float*)d_in[5];
  const int* ori = (const int*)d_in[6];
  const int* head = (const int*)d_in[7];
  const float* tok_emb = (const float*)d_in[8];
  const float* seg_emb = (const float*)d_in[9];
  const float* pool_w = (const float*)d_in[10];
  const float* pool_b = (const float*)d_in[11];
  const float* ln_a = (const float*)d_in[12];
  const float* ln_b = (const float*)d_in[13];
  const float* dep_emb = (const float*)d_in[14];
  const float* fc1_w = (const float*)d_in[15];
  const float* fc1_b = (const float*)d_in[16];
  const float* fc2_w = (const float*)d_in[17];
  const float* fc2_b = (const float*)d_in[18];
  const float* aq_w = (const float*)d_in[19];
  const float* aq_b = (const float*)d_in[20];
  const float* ak_w = (const float*)d_in[21];
  const float* ak_b = (const float*)d_in[22];
  const float* lq_w = (const float*)d_in[23];
  const float* lq_b = (const float*)d_in[24];
  const float* lk_w = (const float*)d_in[25];
  const float* lk_b = (const float*)d_in[26];
  const float* root_w = (const float*)d_in[27];
  const float* gcn_w = (const float*)d_in[28];
  const float* gcn_b = (const float*)d_in[29];
  const float* fc3_w = (const float*)d_in[30];
  const float* fc3_b = (const float*)d_in[31];
  const float* cls_w = (const float*)d_in[32];
  const float* cls_b = (const float*)d_in[33];
  const float* vlin_w = (const float*)d_in[34];

  float* out = (float*)d_out;
  float* ws = (float*)d_ws;
  // fp32 region
  float* gcnH = ws;            // BLD (H2 f32, written by layer-1 fc3)
  float* Isem = gcnH + BLD;    // BLD
  float* depfeat = Isem + BLD;         // B*L
  float* s45 = depfeat + cB * cL;      // 64
  float* pooled = s45 + 64;            // B*D (unused)
  float* x64 = pooled + cB * cD;       // B*D
  float* hlsum = x64 + cB * cD;        // B*D  --- zeroed region start
  float* outputs = hlsum + cB * cD;    // B*D
  float* sempool = outputs + cB * cD;  // B*D
  float* pacc = sempool + cB * cD;     // B*D  --- zeroed region end
  float* e1 = pacc + cB * cD;          // B*L
  float* e2 = e1 + cB * cL;            // B*L
  float* sraw = e2 + cB * cL;          // B*L
  float* wgt = sraw + cB * cL;         // B*L
  float* asum = wgt + cB * cL;         // 64
  float* catb = asum + 64;             // 3072
  // bf16 region
  __hip_bfloat16* gib = (__hip_bfloat16*)(catb + 3072);  // BLD (H state, bf16)
  __hip_bfloat16* qkb = gib + BLD;             // 4*BLD (q|k|q2|k2, ldc=3072)
  __hip_bfloat16* scores = qkb + 4 * BLD;      // (unused, kept for layout)
  __hip_bfloat16* adjag_b = scores + 8 * BLL;  // BLL
  __hip_bfloat16* adjlat_b = adjag_b + BLL;    // BLL
  __hip_bfloat16* wbt = adjlat_b + BLL;        // 7*D*D
  // aliases
  __hip_bfloat16* HWbT = qkb + BLD;     // BLD (HW^T, written directly by EPI=4)
  __hip_bfloat16* Icb = qkb + 2 * BLD;  // BLD

  hipMemsetAsync((char*)d_out + 192 * sizeof(float), 0, 2 * sizeof(float), stream);
  hipMemsetAsync(hlsum, 0, 4 * cB * cD * sizeof(float), stream);

  // ---- prologue ----
  k_gcnin<<<cB * cL / 4, 256, 0, stream>>>(tbi, bsi, tok_emb, seg_emb, ln_a, ln_b,
                                           root_w, gib, x64, e1);
  k_s45<<<45, 256, 0, stream>>>(dep_emb, fc1_w, fc1_b, fc2_w, fc2_b, s45);
  k_depfeat<<<cB, 256, 0, stream>>>(ori, src_mask, s45, depfeat);
  k_pool1<<<dim3(16, 3, 4), 256, 0, stream>>>(x64, pool_w, pacc);
  k_wconv7<<<dim3(24, 24, 8), dim3(32, 8), 0, stream>>>(
      aq_w, ak_w, lq_w, lk_w, gcn_w, gcn_w + (long)cD * cD, fc3_w, wbt,
      aq_b, ak_b, lq_b, lk_b, catb);

  const long DD = (long)cD * cD;
  const long LD = cLD;

  // ---- fused 4-way projection: qkb = gib @ [aq|ak|lq|lk] + catb (XCD-swizzled) ----
  bgemm<1, 0, 1, 0, 1><<<dim3(24, 128, 1), 256, 0, stream>>>(
      gib, wbt, qkb, catb, nullptr, nullptr, cD, cD, cD, 3072,
      0, 0, 0, 0, 0, 0, 0, 0);

  // ---- fused adjacency builders (one dispatch, both variants co-fill) ----
  k_qkadj2<<<dim3(4, cB, 2), 256, 0, stream>>>(qkb, src_mask, head, depfeat,
                                               adjag_b, adjlat_b);

  // ---- GCN loop ----
  for (int layer = 0; layer < 2; layer++) {
    const float* bb = gcn_b + (long)layer * cD;
    // HW^T = (H @ W)^T written directly (EPI=4), layout (b, d, l)
    bgemm<1, 0, 0, 4, 1><<<dim3(6, 128, 1), 256, 0, stream>>>(
        gib, wbt + (4 + layer) * DD, HWbT, nullptr, nullptr, nullptr,
        cD, cD, cD, cD, 0, 0, 0, 0, 0, 0, LD, 0);
    // dual adjacency GEMM + fused I_com epilogue (writes Isem f32 on last layer)
    bgemm_dual<<<dim3(6, 2, cB), 256, 0, stream>>>(
        adjag_b, adjlat_b, HWbT, Isem, Icb, bb, layer == 1 ? 1 : 0);
    // fc3 GEMM + H-gate epilogue on bf16 H (gib); f32 H only on last layer (tail)
    bgemm<0, 1, 1, 2, 1><<<dim3(6, 128, 1), 256, 0, stream>>>(
        Icb, wbt + 6 * DD, nullptr, fc3_b, layer == 1 ? gcnH : nullptr, gib,
        cD, cD, cD, cD, 0, 0, 0, 0, 0, 0, 0, 0);
  }

  // ---- tail ----
  k_hl<<<dim3(8, 3, cB), 256, 0, stream>>>(gcnH, src_mask, hlsum);
  k_rowdot2<<<dim3(cB * cL / 4, 2), 256, 0, stream>>>(Isem, hlsum, gcnH, vlin_w,
                                                      sraw, e2);
  k_tailred<<<cB, 256, 0, stream>>>(sraw, e1, e2, src_mask, aspect_mask, lex,
                                    wgt, asum, out + 192, out + 193);
  k_wsum<<<dim3(8, 3, cB), 256, 0, stream>>>(Isem, wgt, aspect_mask, outputs, sempool);
  k_logits<<<cB, 256, 0, stream>>>(outputs, sempool, pacc, pool_b, asum,
                                   cls_w, cls_b, out);
}